// Round 3
// baseline (1010.261 us; speedup 1.0000x reference)
//
#include <hip/hip_runtime.h>

#define NN 50000
#define HECNT 10000
#define EE 800000
#define II 800000

typedef _Float16 h2   __attribute__((ext_vector_type(2)));
typedef _Float16 half8 __attribute__((ext_vector_type(8)));
typedef float f32x4   __attribute__((ext_vector_type(4)));

// ---------------- index-width detection ----------------
// int64 little-endian nonneg indices => odd int32 words are all zero.
__global__ void detect_k(const int* __restrict__ EIX, const int* __restrict__ HIX,
                         int* __restrict__ flags) {
    __shared__ int o0, o1;
    int tid = threadIdx.x;
    if (tid == 0) { o0 = 0; o1 = 0; }
    __syncthreads();
    atomicOr(&o0, EIX[2 * tid + 1]);
    atomicOr(&o1, HIX[2 * tid + 1]);
    __syncthreads();
    if (tid == 0) { flags[0] = (o0 == 0); flags[1] = (o1 == 0); }
}

__device__ __forceinline__ int ld_idx(const int* p, long long pos, int is64) {
    return is64 ? p[pos * 2] : p[(int)pos];
}

// ---------------- CSR build ----------------
__device__ __forceinline__ void task_info(int t, int& n, int& cbase, int& obase) {
    if (t == 0)      { n = HECNT; cbase = 0;           obase = 0; }
    else if (t == 1) { n = NN;    cbase = HECNT;       obase = HECNT + 1; }
    else             { n = NN;    cbase = HECNT + NN;  obase = HECNT + NN + 2; }
}

__global__ __launch_bounds__(256) void hist_k(const int* __restrict__ EIX,
                                              const int* __restrict__ HIX,
                                              const int* __restrict__ flags,
                                              int* __restrict__ counts) {
    int t = blockIdx.y;
    int i = blockIdx.x * 256 + threadIdx.x;
    if (i >= EE) return;
    int d, cb, rng;
    if (t == 0)      { d = ld_idx(HIX, (long long)II + i, flags[1]); cb = 0;          rng = HECNT; }
    else if (t == 1) { d = ld_idx(HIX, i,                 flags[1]); cb = HECNT;      rng = NN; }
    else             { d = ld_idx(EIX, (long long)EE + i, flags[0]); cb = HECNT + NN; rng = NN; }
    if ((unsigned)d < (unsigned)rng) atomicAdd(&counts[cb + d], 1);
}

__global__ __launch_bounds__(256) void scan_p1(const int* __restrict__ counts,
                                               int* __restrict__ bsums) {
    int t = blockIdx.y;
    int n, cb, ob; task_info(t, n, cb, ob);
    int base = blockIdx.x * 1024 + threadIdx.x * 4;
    int s = 0;
    #pragma unroll
    for (int j = 0; j < 4; j++) { int i = base + j; if (i < n) s += counts[cb + i]; }
    __shared__ int red[256];
    red[threadIdx.x] = s; __syncthreads();
    for (int o = 128; o > 0; o >>= 1) {
        if (threadIdx.x < o) red[threadIdx.x] += red[threadIdx.x + o];
        __syncthreads();
    }
    if (threadIdx.x == 0) bsums[t * 64 + blockIdx.x] = red[0];
}

__global__ void scan_p2(int* __restrict__ bsums, int* __restrict__ offs) {
    int t = blockIdx.y;
    int n, cb, ob; task_info(t, n, cb, ob);
    int lane = threadIdx.x;
    int nb = (n + 1023) / 1024;
    int v = (lane < nb) ? bsums[t * 64 + lane] : 0;
    int incl = v;
    for (int d = 1; d < 64; d <<= 1) {
        int u = __shfl_up(incl, (unsigned)d, 64);
        if (lane >= d) incl += u;
    }
    bsums[t * 64 + lane] = incl - v;           // exclusive block sums
    int total = __shfl(incl, 63, 64);
    if (lane == 0) offs[ob + n] = total;
}

__global__ __launch_bounds__(256) void scan_p3(const int* __restrict__ counts,
                                               const int* __restrict__ bsums,
                                               int* __restrict__ offs,
                                               int* __restrict__ cursor) {
    int t = blockIdx.y;
    int n, cb, ob; task_info(t, n, cb, ob);
    int tid = threadIdx.x;
    int base = blockIdx.x * 1024 + tid * 4;
    int c[4]; int s = 0;
    #pragma unroll
    for (int j = 0; j < 4; j++) { int i = base + j; c[j] = (i < n) ? counts[cb + i] : 0; s += c[j]; }
    __shared__ int sc[256];
    sc[tid] = s; __syncthreads();
    for (int o = 1; o < 256; o <<= 1) {
        int v = (tid >= o) ? sc[tid - o] : 0;
        __syncthreads();
        sc[tid] += v;
        __syncthreads();
    }
    int excl = sc[tid] - s;
    int p = bsums[t * 64 + blockIdx.x] + excl;
    #pragma unroll
    for (int j = 0; j < 4; j++) {
        int i = base + j;
        if (i < n) { offs[ob + i] = p; cursor[cb + i] = p; p += c[j]; }
    }
}

__global__ __launch_bounds__(256) void fill_k(const int* __restrict__ EIX,
                                              const int* __restrict__ HIX,
                                              const int* __restrict__ flags,
                                              int* __restrict__ cursor,
                                              int* __restrict__ vals) {
    int t = blockIdx.y;
    int i = blockIdx.x * 256 + threadIdx.x;
    if (i >= EE) return;
    int d, v, cb, rng;
    if (t == 0) {
        d = ld_idx(HIX, (long long)II + i, flags[1]);
        v = ld_idx(HIX, i,                 flags[1]);
        cb = 0; rng = HECNT;
    } else if (t == 1) {
        d = ld_idx(HIX, i,                 flags[1]);
        v = ld_idx(HIX, (long long)II + i, flags[1]);
        cb = HECNT; rng = NN;
    } else {
        d = ld_idx(EIX, (long long)EE + i, flags[0]);
        v = ld_idx(EIX, i,                 flags[0]);
        cb = HECNT + NN; rng = NN;
    }
    if ((unsigned)d >= (unsigned)rng) return;
    int p = atomicAdd(&cursor[cb + d], 1);
    if ((unsigned)p < 800000u) vals[t * 800000 + p] = v;
}

// ------- gather (segment-sum over CSR), feature-parallel; src f32 or f16, dst f16 -------
template <typename ST>
__global__ __launch_bounds__(256) void gather_k(const int* __restrict__ offs,
                                                const int* __restrict__ vals,
                                                const ST* __restrict__ src,     // [S x 128]
                                                _Float16* __restrict__ out,     // [ndst x 128]
                                                int ndst, int nsrc, int scale_flag,
                                                const float* __restrict__ bias,
                                                int act) {
    int wave = threadIdx.x >> 6, lane = threadIdx.x & 63;
    int d = blockIdx.x * 4 + wave;
    if (d >= ndst) return;
    int beg = offs[d], end = offs[d + 1];
    int f = lane * 2;
    float a0 = 0.f, a1 = 0.f;
    auto acc_one = [&](int s0) {
        if ((unsigned)s0 < (unsigned)nsrc) {
            if constexpr (sizeof(ST) == 4) {
                float2 u = *(const float2*)(src + (size_t)s0 * 128 + f);
                a0 += u.x; a1 += u.y;
            } else {
                h2 u = *(const h2*)(src + (size_t)s0 * 128 + f);
                a0 += (float)u.x; a1 += (float)u.y;
            }
        }
    };
    int e = beg;
    for (; e + 1 < end; e += 2) { int s0 = vals[e], s1 = vals[e + 1]; acc_one(s0); acc_one(s1); }
    if (e < end) acc_one(vals[e]);
    if (scale_flag) {
        int c = end - beg;
        float iv = (c > 0) ? 1.f / (float)c : 0.f;
        a0 *= iv; a1 *= iv;
    }
    if (bias) { a0 += bias[f]; a1 += bias[f + 1]; }
    if (act)  { a0 = (a0 >= 0.f) ? a0 : 0.01f * a0; a1 = (a1 >= 0.f) ? a1 : 0.01f * a1; }
    h2 o; o.x = (_Float16)a0; o.y = (_Float16)a1;
    *(h2*)(out + (size_t)d * 128 + f) = o;
}

// ---- MFMA GEMM (f16 matrix cores, f32 accumulate):
//      C[MxN] = act(A[Mx128] @ W[128xN] + bias + bias2 + addend)      (in-place A==C safe:
//      each wave reads A only from its own 32-row band, writes the same band after all reads)
template <int N, typename AT, typename CT>
__global__ __launch_bounds__(256) void gemm_k(const AT* __restrict__ A,
                                              const float* __restrict__ W,    // [128 x N]
                                              const float* __restrict__ bias,
                                              const float* __restrict__ bias2,
                                              const _Float16* __restrict__ addend,  // [M x N]
                                              CT* __restrict__ C,
                                              int M, int act) {
    constexpr int K = 128;
    constexpr int LDT = K + 8;   // 272B rows: 16B-aligned, 2-way bank alias (free per m136)
    constexpr int NT = N / 16;
    __shared__ _Float16 Wt[N * LDT];
    int tid = threadIdx.x;
    for (int idx = tid; idx < K * N; idx += 256) {
        int k = idx / N, n = idx % N;
        Wt[n * LDT + k] = (_Float16)W[idx];
    }
    __syncthreads();

    int wave = tid >> 6, lane = tid & 63;
    int quad = lane >> 4, l16 = lane & 15;
    int rowbase = blockIdx.x * 128 + wave * 32;

    f32x4 acc[2][NT];
    f32x4 zero4 = {0.f, 0.f, 0.f, 0.f};
    #pragma unroll
    for (int mt = 0; mt < 2; mt++)
        #pragma unroll
        for (int nt = 0; nt < NT; nt++) acc[mt][nt] = zero4;

    #pragma unroll
    for (int ks = 0; ks < 4; ks++) {
        int k0 = ks * 32 + quad * 8;
        half8 af[2];
        #pragma unroll
        for (int mt = 0; mt < 2; mt++) {
            int row = rowbase + mt * 16 + l16;
            half8 v = {0, 0, 0, 0, 0, 0, 0, 0};
            if (row < M) {
                if constexpr (sizeof(AT) == 4) {
                    const float* ap = A + (size_t)row * K + k0;
                    float4 x0 = *(const float4*)ap;
                    float4 x1 = *(const float4*)(ap + 4);
                    v = half8{(_Float16)x0.x, (_Float16)x0.y, (_Float16)x0.z, (_Float16)x0.w,
                              (_Float16)x1.x, (_Float16)x1.y, (_Float16)x1.z, (_Float16)x1.w};
                } else {
                    v = *(const half8*)(A + (size_t)row * K + k0);
                }
            }
            af[mt] = v;
        }
        #pragma unroll
        for (int nt = 0; nt < NT; nt++) {
            half8 bfr = *(const half8*)(&Wt[(nt * 16 + l16) * LDT + k0]);
            #pragma unroll
            for (int mt = 0; mt < 2; mt++)
                acc[mt][nt] = __builtin_amdgcn_mfma_f32_16x16x32_f16(af[mt], bfr, acc[mt][nt], 0, 0, 0);
        }
    }

    #pragma unroll
    for (int nt = 0; nt < NT; nt++) {
        int col = nt * 16 + l16;
        float bv = 0.f;
        if (bias)  bv += bias[col];
        if (bias2) bv += bias2[col];
        #pragma unroll
        for (int mt = 0; mt < 2; mt++) {
            #pragma unroll
            for (int r = 0; r < 4; r++) {
                int row = rowbase + mt * 16 + quad * 4 + r;
                if (row < M) {
                    float v = acc[mt][nt][r] + bv;
                    if (addend) v += (float)addend[(size_t)row * N + col];
                    if (act) v = (v >= 0.f) ? v : 0.01f * v;
                    C[(size_t)row * N + col] = (CT)v;
                }
            }
        }
    }
}

// ---------------- tiny: Wc = a + b (f32, 16384 elems) ----------------
__global__ __launch_bounds__(256) void wadd_k(const float* __restrict__ a,
                                              const float* __restrict__ b,
                                              float* __restrict__ o) {
    int i = blockIdx.x * 256 + threadIdx.x;
    if (i < 16384) o[i] = a[i] + b[i];
}

extern "C" void kernel_launch(void* const* d_in, const int* in_sizes, int n_in,
                              void* d_out, int out_size, void* d_ws, size_t ws_size,
                              hipStream_t stream) {
    const float* X       = (const float*)d_in[0];
    const int*   EIX     = (const int*)d_in[1];
    const int*   HIX     = (const int*)d_in[2];
    const float* hc1_w   = (const float*)d_in[3];
    const float* hc1_b   = (const float*)d_in[4];
    const float* lin1_w  = (const float*)d_in[5];
    const float* lin1_b  = (const float*)d_in[6];
    const float* hc2_w   = (const float*)d_in[7];
    const float* hc2_b   = (const float*)d_in[8];
    const float* lin2_w  = (const float*)d_in[9];
    const float* lin2_b  = (const float*)d_in[10];
    const float* c1_wrel = (const float*)d_in[11];
    const float* c1_brel = (const float*)d_in[12];
    const float* c1_wroot= (const float*)d_in[13];
    const float* glin1_w = (const float*)d_in[14];
    const float* glin1_b = (const float*)d_in[15];
    const float* c2_wrel = (const float*)d_in[16];
    const float* c2_brel = (const float*)d_in[17];
    const float* c2_wroot= (const float*)d_in[18];
    const float* glin2_w = (const float*)d_in[19];
    const float* glin2_b = (const float*)d_in[20];
    const float* fc_w    = (const float*)d_in[21];
    const float* fc_b    = (const float*)d_in[22];

    // ---- workspace carve (total ~26.4 MB) ----
    char* wsp = (char*)d_ws;
    size_t off = 0;
    auto carve = [&](size_t bytes) -> char* {
        char* p = wsp + off;
        off = (off + bytes + 255) & ~(size_t)255;
        return p;
    };
    int*      flags  = (int*)carve(16);
    int*      counts = (int*)carve(110000 * 4);
    int*      offs   = (int*)carve(110003 * 4);
    int*      cursor = (int*)carve(110000 * 4);
    int*      bsums  = (int*)carve(192 * 4);
    float*    Wc     = (float*)carve(16384 * 4);
    int*      vals   = (int*)carve(2400000 * 4);
    _Float16* P      = (_Float16*)carve((size_t)NN * 128 * 2);     // 12.8 MB scratch (f16)
    _Float16* MH     = (_Float16*)carve((size_t)HECNT * 128 * 2);  // 2.56 MB (f16)

    float* XO = (float*)d_out;                 // final X: 50000 x 128 f32 (activation chain, in-place)
    float* YO = XO + (size_t)NN * 128;         // final y: 50000 x 64 f32

    // ---- CSR build (index-width adaptive) ----
    hipMemsetAsync(counts, 0, 110000 * 4, stream);
    detect_k<<<1, 256, 0, stream>>>(EIX, HIX, flags);
    hist_k<<<dim3(3125, 3), 256, 0, stream>>>(EIX, HIX, flags, counts);
    scan_p1<<<dim3(49, 3), 256, 0, stream>>>(counts, bsums);
    scan_p2<<<dim3(1, 3), 64, 0, stream>>>(bsums, offs);
    scan_p3<<<dim3(49, 3), 256, 0, stream>>>(counts, bsums, offs, cursor);
    fill_k<<<dim3(3125, 3), 256, 0, stream>>>(EIX, HIX, flags, cursor, vals);

    const int* offs_he   = offs;                    // [HECNT+1]
    const int* offs_node = offs + HECNT + 1;        // [NN+1]
    const int* offs_dst  = offs + HECNT + NN + 2;   // [NN+1]
    const int* vals_he   = vals;
    const int* vals_node = vals + 800000;
    const int* vals_dst  = vals + 1600000;

    int gg  = (NN + 127) / 128;       // 391
    int ghe = (HECNT + 3) / 4;        // 2500
    int gnn = (NN + 3) / 4;           // 12500

    // ---- Layer 1: X1 = leaky(HGC(X) + X@lin1 + lin1_b) ----
    gemm_k<128, float, _Float16><<<gg, 256, 0, stream>>>(X, hc1_w, nullptr, nullptr, nullptr, P, NN, 0);   // P = X@theta1
    gather_k<_Float16><<<ghe, 256, 0, stream>>>(offs_he, vals_he, P, MH, HECNT, NN, 1, nullptr, 0);        // MH = Binv H^T P
    gather_k<_Float16><<<gnn, 256, 0, stream>>>(offs_node, vals_node, MH, P, NN, HECNT, 1, hc1_b, 0);      // P = Dinv H MH + hc1_b
    gemm_k<128, float, float><<<gg, 256, 0, stream>>>(X, lin1_w, lin1_b, nullptr, P, XO, NN, 1);           // XO = leaky(X@lin1 + b + P)

    // ---- Layer 2 ----
    gemm_k<128, float, _Float16><<<gg, 256, 0, stream>>>(XO, hc2_w, nullptr, nullptr, nullptr, P, NN, 0);
    gather_k<_Float16><<<ghe, 256, 0, stream>>>(offs_he, vals_he, P, MH, HECNT, NN, 1, nullptr, 0);
    gather_k<_Float16><<<gnn, 256, 0, stream>>>(offs_node, vals_node, MH, P, NN, HECNT, 1, hc2_b, 0);
    gemm_k<128, float, float><<<gg, 256, 0, stream>>>(XO, lin2_w, lin2_b, nullptr, P, XO, NN, 1);          // in-place

    // ---- Layer 3: X3 = leaky(AGG@Wrel + brel + X2@(Wroot+glin1_w) + glin1_b) ----
    wadd_k<<<64, 256, 0, stream>>>(c1_wroot, glin1_w, Wc);
    gather_k<float><<<gnn, 256, 0, stream>>>(offs_dst, vals_dst, XO, P, NN, NN, 0, nullptr, 0);            // P = AGG (f16)
    gemm_k<128, _Float16, _Float16><<<gg, 256, 0, stream>>>(P, c1_wrel, c1_brel, nullptr, nullptr, P, NN, 0); // P = AGG@Wrel + brel
    gemm_k<128, float, float><<<gg, 256, 0, stream>>>(XO, Wc, glin1_b, nullptr, P, XO, NN, 1);             // in-place

    // ---- Layer 4 ----
    wadd_k<<<64, 256, 0, stream>>>(c2_wroot, glin2_w, Wc);
    gather_k<float><<<gnn, 256, 0, stream>>>(offs_dst, vals_dst, XO, P, NN, NN, 0, nullptr, 0);
    gemm_k<128, _Float16, _Float16><<<gg, 256, 0, stream>>>(P, c2_wrel, c2_brel, nullptr, nullptr, P, NN, 0);
    gemm_k<128, float, float><<<gg, 256, 0, stream>>>(XO, Wc, glin2_b, nullptr, P, XO, NN, 1);             // in-place; XO final

    // ---- fc head ----
    gemm_k<64, float, float><<<gg, 256, 0, stream>>>(XO, fc_w, fc_b, nullptr, nullptr, YO, NN, 0);
}

// Round 4
// 880.881 us; speedup vs baseline: 1.1469x; 1.1469x over previous
//
#include <hip/hip_runtime.h>

#define NN 50000
#define HECNT 10000
#define EE 800000
#define II 800000
#define NBK 128          // buckets per task (counting sort)
#define CHUNK 4096       // edges per workgroup in bin_k
#define BCAP 12288       // max edges per bucket staged in LDS (avg ~6300)

typedef _Float16 h2    __attribute__((ext_vector_type(2)));
typedef _Float16 half8 __attribute__((ext_vector_type(8)));
typedef float f32x4    __attribute__((ext_vector_type(4)));

// ---------------- index-width detection ----------------
// int64 little-endian nonneg indices => odd int32 words are all zero.
__global__ void detect_k(const int* __restrict__ EIX, const int* __restrict__ HIX,
                         int* __restrict__ flags) {
    __shared__ int o0, o1;
    int tid = threadIdx.x;
    if (tid == 0) { o0 = 0; o1 = 0; }
    __syncthreads();
    atomicOr(&o0, EIX[2 * tid + 1]);
    atomicOr(&o1, HIX[2 * tid + 1]);
    __syncthreads();
    if (tid == 0) { flags[0] = (o0 == 0); flags[1] = (o1 == 0); }
}

__device__ __forceinline__ int ld_idx(const int* p, long long pos, int is64) {
    return is64 ? p[pos * 2] : p[(int)pos];
}

// ---------------- CSR build ----------------
__device__ __forceinline__ void task_info(int t, int& n, int& cbase, int& obase) {
    if (t == 0)      { n = HECNT; cbase = 0;           obase = 0; }
    else if (t == 1) { n = NN;    cbase = HECNT;       obase = HECNT + 1; }
    else             { n = NN;    cbase = HECNT + NN;  obase = HECNT + NN + 2; }
}

// load (dest, val) for incidence/edge i of task t; dest<0 if invalid
__device__ __forceinline__ void ld_edge(int t, long long i,
                                        const int* EIX, const int* HIX,
                                        int f0, int f1, int& d, int& v) {
    int rng;
    if (t == 0)      { d = ld_idx(HIX, (long long)II + i, f1); v = ld_idx(HIX, i, f1); rng = HECNT; }
    else if (t == 1) { d = ld_idx(HIX, i, f1); v = ld_idx(HIX, (long long)II + i, f1); rng = NN; }
    else             { d = ld_idx(EIX, (long long)EE + i, f0); v = ld_idx(EIX, i, f0); rng = NN; }
    if ((unsigned)d >= (unsigned)rng) d = -1;
}

__global__ __launch_bounds__(256) void hist_k(const int* __restrict__ EIX,
                                              const int* __restrict__ HIX,
                                              const int* __restrict__ flags,
                                              int* __restrict__ counts) {
    int t = blockIdx.y;
    int i = blockIdx.x * 256 + threadIdx.x;
    if (i >= EE) return;
    int cb = (t == 0) ? 0 : (t == 1 ? HECNT : HECNT + NN);
    int d, v;
    ld_edge(t, i, EIX, HIX, flags[0], flags[1], d, v);
    if (d >= 0) atomicAdd(&counts[cb + d], 1);
}

__global__ __launch_bounds__(256) void scan_p1(const int* __restrict__ counts,
                                               int* __restrict__ bsums) {
    int t = blockIdx.y;
    int n, cb, ob; task_info(t, n, cb, ob);
    int base = blockIdx.x * 1024 + threadIdx.x * 4;
    int s = 0;
    #pragma unroll
    for (int j = 0; j < 4; j++) { int i = base + j; if (i < n) s += counts[cb + i]; }
    __shared__ int red[256];
    red[threadIdx.x] = s; __syncthreads();
    for (int o = 128; o > 0; o >>= 1) {
        if (threadIdx.x < o) red[threadIdx.x] += red[threadIdx.x + o];
        __syncthreads();
    }
    if (threadIdx.x == 0) bsums[t * 64 + blockIdx.x] = red[0];
}

__global__ void scan_p2(int* __restrict__ bsums, int* __restrict__ offs) {
    int t = blockIdx.y;
    int n, cb, ob; task_info(t, n, cb, ob);
    int lane = threadIdx.x;
    int nb = (n + 1023) / 1024;
    int v = (lane < nb) ? bsums[t * 64 + lane] : 0;
    int incl = v;
    for (int d = 1; d < 64; d <<= 1) {
        int u = __shfl_up(incl, (unsigned)d, 64);
        if (lane >= d) incl += u;
    }
    bsums[t * 64 + lane] = incl - v;           // exclusive block sums
    int total = __shfl(incl, 63, 64);
    if (lane == 0) offs[ob + n] = total;
}

__global__ __launch_bounds__(256) void scan_p3(const int* __restrict__ counts,
                                               const int* __restrict__ bsums,
                                               int* __restrict__ offs,
                                               int* __restrict__ cursor) {
    int t = blockIdx.y;
    int n, cb, ob; task_info(t, n, cb, ob);
    int tid = threadIdx.x;
    int base = blockIdx.x * 1024 + tid * 4;
    int c[4]; int s = 0;
    #pragma unroll
    for (int j = 0; j < 4; j++) { int i = base + j; c[j] = (i < n) ? counts[cb + i] : 0; s += c[j]; }
    __shared__ int sc[256];
    sc[tid] = s; __syncthreads();
    for (int o = 1; o < 256; o <<= 1) {
        int v = (tid >= o) ? sc[tid - o] : 0;
        __syncthreads();
        sc[tid] += v;
        __syncthreads();
    }
    int excl = sc[tid] - s;
    int p = bsums[t * 64 + blockIdx.x] + excl;
    #pragma unroll
    for (int j = 0; j < 4; j++) {
        int i = base + j;
        if (i < n) { offs[ob + i] = p; cursor[cb + i] = p; p += c[j]; }
    }
}

// legacy fallback fill (random 4B scatter) — used only if ws too small for staging
__global__ __launch_bounds__(256) void fill_k(const int* __restrict__ EIX,
                                              const int* __restrict__ HIX,
                                              const int* __restrict__ flags,
                                              int* __restrict__ cursor,
                                              int* __restrict__ vals) {
    int t = blockIdx.y;
    int i = blockIdx.x * 256 + threadIdx.x;
    if (i >= EE) return;
    int cb = (t == 0) ? 0 : (t == 1 ? HECNT : HECNT + NN);
    int d, v;
    ld_edge(t, i, EIX, HIX, flags[0], flags[1], d, v);
    if (d < 0) return;
    int p = atomicAdd(&cursor[cb + d], 1);
    if ((unsigned)p < 800000u) vals[t * 800000 + p] = v;
}

// ---- bucket cursor init: staging bucket base = CSR offset of bucket's first dest ----
__global__ void binit_k(const int* __restrict__ offs, int* __restrict__ bcur) {
    int i = blockIdx.x * 256 + threadIdx.x;
    if (i >= 3 * NBK) return;
    int t = i / NBK, b = i % NBK;
    int n, cb, ob; task_info(t, n, cb, ob);
    int span = (n + NBK - 1) / NBK;
    int dlo = min(b * span, n);
    bcur[i] = offs[ob + dlo] + t * 800000;
}

// ---- phase A: bin edges into coarse-bucket staging with >=256B contiguous write runs ----
__global__ __launch_bounds__(256) void bin_k(const int* __restrict__ EIX,
                                             const int* __restrict__ HIX,
                                             const int* __restrict__ flags,
                                             int* __restrict__ bcur,
                                             uint2* __restrict__ pairs) {
    int t = blockIdx.y;
    __shared__ int hcnt[NBK], hstart[NBK], hrun[NBK], gbase[NBK];
    __shared__ int stot;
    __shared__ uint2 stage[CHUNK];       // 32 KB
    int tid = threadIdx.x;
    int n, cb, ob; task_info(t, n, cb, ob);
    int span = (n + NBK - 1) / NBK;
    long long base = (long long)blockIdx.x * CHUNK;
    int f0 = flags[0], f1 = flags[1];

    for (int i = tid; i < NBK; i += 256) { hcnt[i] = 0; hrun[i] = 0; }
    __syncthreads();

    int d[16], v[16], b[16];
    #pragma unroll
    for (int j = 0; j < 16; j++) {
        long long i = base + j * 256 + tid;
        int dd = -1, vv = 0;
        if (i < EE) ld_edge(t, i, EIX, HIX, f0, f1, dd, vv);
        d[j] = dd; v[j] = vv;
        if (dd >= 0) { b[j] = dd / span; atomicAdd(&hcnt[b[j]], 1); }
    }
    __syncthreads();

    // reserve global runs
    if (tid < NBK) gbase[tid] = hcnt[tid] ? atomicAdd(&bcur[t * NBK + tid], hcnt[tid]) : 0;
    // inclusive prefix of hcnt into hstart
    if (tid < NBK) hstart[tid] = hcnt[tid];
    __syncthreads();
    for (int o = 1; o < NBK; o <<= 1) {
        int u = 0;
        if (tid < NBK && tid >= o) u = hstart[tid - o];
        __syncthreads();
        if (tid < NBK) hstart[tid] += u;
        __syncthreads();
    }
    if (tid == NBK - 1) stot = hstart[tid];
    __syncthreads();
    if (tid < NBK) hstart[tid] -= hcnt[tid];   // exclusive
    __syncthreads();

    // scatter into LDS stage (bucket-sorted order)
    #pragma unroll
    for (int j = 0; j < 16; j++) {
        if (d[j] >= 0) {
            int p = hstart[b[j]] + atomicAdd(&hrun[b[j]], 1);
            stage[p] = make_uint2((unsigned)d[j], (unsigned)v[j]);
        }
    }
    __syncthreads();

    // flush runs to global staging (coalesced within each run)
    int total = stot;
    for (int i = tid; i < total; i += 256) {
        int lo = 0, hi = NBK - 1;                  // last bucket with hstart <= i
        while (lo < hi) { int mid = (lo + hi + 1) >> 1; if (hstart[mid] <= i) lo = mid; else hi = mid - 1; }
        pairs[gbase[lo] + (i - hstart[lo])] = stage[i];
    }
}

// ---- phase B: per-bucket exact CSR placement via LDS window, coalesced flush ----
__global__ __launch_bounds__(256) void unbin_k(const int* __restrict__ offs,
                                               const uint2* __restrict__ pairs,
                                               int* __restrict__ vals) {
    int idx = blockIdx.x;              // 0 .. 3*NBK-1
    int t = idx / NBK, b = idx % NBK;
    int n, cb, ob; task_info(t, n, cb, ob);
    int span = (n + NBK - 1) / NBK;
    int dlo = min(b * span, n), dhi = min(dlo + span, n);
    if (dhi <= dlo) return;
    int p0 = offs[ob + dlo], p1 = offs[ob + dhi];
    int cnt = p1 - p0;
    __shared__ int win[BCAP];          // 48 KB
    __shared__ int cur[400];
    int tid = threadIdx.x;
    for (int i = tid; i < dhi - dlo; i += 256) cur[i] = offs[ob + dlo + i] - p0;
    __syncthreads();
    const uint2* pw = pairs + (size_t)t * 800000 + p0;
    int* vw = vals + (size_t)t * 800000 + p0;
    if (cnt <= BCAP) {
        for (int i = tid; i < cnt; i += 256) {
            uint2 pv = pw[i];
            int p = atomicAdd(&cur[(int)pv.x - dlo], 1);
            win[p] = (int)pv.y;
        }
        __syncthreads();
        for (int i = tid; i < cnt; i += 256) vw[i] = win[i];
    } else {
        for (int i = tid; i < cnt; i += 256) {   // slow path (never expected)
            uint2 pv = pw[i];
            int p = atomicAdd(&cur[(int)pv.x - dlo], 1);
            vw[p] = (int)pv.y;
        }
    }
}

// ------- gather (segment-sum over CSR), feature-parallel; src f32 or f16, dst f16 -------
template <typename ST>
__global__ __launch_bounds__(256) void gather_k(const int* __restrict__ offs,
                                                const int* __restrict__ vals,
                                                const ST* __restrict__ src,     // [S x 128]
                                                _Float16* __restrict__ out,     // [ndst x 128]
                                                int ndst, int nsrc, int scale_flag,
                                                const float* __restrict__ bias,
                                                int act) {
    int wave = threadIdx.x >> 6, lane = threadIdx.x & 63;
    int d = blockIdx.x * 4 + wave;
    if (d >= ndst) return;
    int beg = offs[d], end = offs[d + 1];
    int f = lane * 2;
    float a0 = 0.f, a1 = 0.f;
    auto acc_one = [&](int s0) {
        if ((unsigned)s0 < (unsigned)nsrc) {
            if constexpr (sizeof(ST) == 4) {
                float2 u = *(const float2*)(src + (size_t)s0 * 128 + f);
                a0 += u.x; a1 += u.y;
            } else {
                h2 u = *(const h2*)(src + (size_t)s0 * 128 + f);
                a0 += (float)u.x; a1 += (float)u.y;
            }
        }
    };
    int e = beg;
    for (; e + 1 < end; e += 2) { int s0 = vals[e], s1 = vals[e + 1]; acc_one(s0); acc_one(s1); }
    if (e < end) acc_one(vals[e]);
    if (scale_flag) {
        int c = end - beg;
        float iv = (c > 0) ? 1.f / (float)c : 0.f;
        a0 *= iv; a1 *= iv;
    }
    if (bias) { a0 += bias[f]; a1 += bias[f + 1]; }
    if (act)  { a0 = (a0 >= 0.f) ? a0 : 0.01f * a0; a1 = (a1 >= 0.f) ? a1 : 0.01f * a1; }
    h2 o; o.x = (_Float16)a0; o.y = (_Float16)a1;
    *(h2*)(out + (size_t)d * 128 + f) = o;
}

// ---- MFMA GEMM (f16 matrix cores, f32 accumulate); A==C in-place safe (no restrict on A/C):
//      C[MxN] = act(A[Mx128] @ W[128xN] + bias + bias2 + addend); optional f16 shadow C2
template <int N, typename AT, typename CT>
__global__ __launch_bounds__(256) void gemm_k(const AT* A,
                                              const float* __restrict__ W,    // [128 x N]
                                              const float* __restrict__ bias,
                                              const float* __restrict__ bias2,
                                              const _Float16* addend,          // [M x N]
                                              CT* C,
                                              _Float16* C2,
                                              int M, int act) {
    constexpr int K = 128;
    constexpr int LDT = K + 8;   // 272B rows: 16B-aligned, 2-way bank alias (free per m136)
    constexpr int NT = N / 16;
    __shared__ _Float16 Wt[N * LDT];
    int tid = threadIdx.x;
    for (int idx = tid; idx < K * N; idx += 256) {
        int k = idx / N, n = idx % N;
        Wt[n * LDT + k] = (_Float16)W[idx];
    }
    __syncthreads();

    int wave = tid >> 6, lane = tid & 63;
    int quad = lane >> 4, l16 = lane & 15;
    int rowbase = blockIdx.x * 128 + wave * 32;

    f32x4 acc[2][NT];
    f32x4 zero4 = {0.f, 0.f, 0.f, 0.f};
    #pragma unroll
    for (int mt = 0; mt < 2; mt++)
        #pragma unroll
        for (int nt = 0; nt < NT; nt++) acc[mt][nt] = zero4;

    #pragma unroll
    for (int ks = 0; ks < 4; ks++) {
        int k0 = ks * 32 + quad * 8;
        half8 af[2];
        #pragma unroll
        for (int mt = 0; mt < 2; mt++) {
            int row = rowbase + mt * 16 + l16;
            half8 v = {0, 0, 0, 0, 0, 0, 0, 0};
            if (row < M) {
                if constexpr (sizeof(AT) == 4) {
                    const float* ap = (const float*)A + (size_t)row * K + k0;
                    float4 x0 = *(const float4*)ap;
                    float4 x1 = *(const float4*)(ap + 4);
                    v = half8{(_Float16)x0.x, (_Float16)x0.y, (_Float16)x0.z, (_Float16)x0.w,
                              (_Float16)x1.x, (_Float16)x1.y, (_Float16)x1.z, (_Float16)x1.w};
                } else {
                    v = *(const half8*)((const _Float16*)A + (size_t)row * K + k0);
                }
            }
            af[mt] = v;
        }
        #pragma unroll
        for (int nt = 0; nt < NT; nt++) {
            half8 bfr = *(const half8*)(&Wt[(nt * 16 + l16) * LDT + k0]);
            #pragma unroll
            for (int mt = 0; mt < 2; mt++)
                acc[mt][nt] = __builtin_amdgcn_mfma_f32_16x16x32_f16(af[mt], bfr, acc[mt][nt], 0, 0, 0);
        }
    }

    #pragma unroll
    for (int nt = 0; nt < NT; nt++) {
        int col = nt * 16 + l16;
        float bv = 0.f;
        if (bias)  bv += bias[col];
        if (bias2) bv += bias2[col];
        #pragma unroll
        for (int mt = 0; mt < 2; mt++) {
            #pragma unroll
            for (int r = 0; r < 4; r++) {
                int row = rowbase + mt * 16 + quad * 4 + r;
                if (row < M) {
                    float v = acc[mt][nt][r] + bv;
                    if (addend) v += (float)addend[(size_t)row * N + col];
                    if (act) v = (v >= 0.f) ? v : 0.01f * v;
                    C[(size_t)row * N + col] = (CT)v;
                    if (C2) C2[(size_t)row * N + col] = (_Float16)v;
                }
            }
        }
    }
}

// ---------------- tiny: Wc = a + b (f32, 16384 elems) ----------------
__global__ __launch_bounds__(256) void wadd_k(const float* __restrict__ a,
                                              const float* __restrict__ b,
                                              float* __restrict__ o) {
    int i = blockIdx.x * 256 + threadIdx.x;
    if (i < 16384) o[i] = a[i] + b[i];
}

extern "C" void kernel_launch(void* const* d_in, const int* in_sizes, int n_in,
                              void* d_out, int out_size, void* d_ws, size_t ws_size,
                              hipStream_t stream) {
    const float* X       = (const float*)d_in[0];
    const int*   EIX     = (const int*)d_in[1];
    const int*   HIX     = (const int*)d_in[2];
    const float* hc1_w   = (const float*)d_in[3];
    const float* hc1_b   = (const float*)d_in[4];
    const float* lin1_w  = (const float*)d_in[5];
    const float* lin1_b  = (const float*)d_in[6];
    const float* hc2_w   = (const float*)d_in[7];
    const float* hc2_b   = (const float*)d_in[8];
    const float* lin2_w  = (const float*)d_in[9];
    const float* lin2_b  = (const float*)d_in[10];
    const float* c1_wrel = (const float*)d_in[11];
    const float* c1_brel = (const float*)d_in[12];
    const float* c1_wroot= (const float*)d_in[13];
    const float* glin1_w = (const float*)d_in[14];
    const float* glin1_b = (const float*)d_in[15];
    const float* c2_wrel = (const float*)d_in[16];
    const float* c2_brel = (const float*)d_in[17];
    const float* c2_wroot= (const float*)d_in[18];
    const float* glin2_w = (const float*)d_in[19];
    const float* glin2_b = (const float*)d_in[20];
    const float* fc_w    = (const float*)d_in[21];
    const float* fc_b    = (const float*)d_in[22];

    // ---- workspace carve ----
    char* wsp = (char*)d_ws;
    size_t off = 0;
    auto carve = [&](size_t bytes) -> char* {
        char* p = wsp + off;
        off = (off + bytes + 255) & ~(size_t)255;
        return p;
    };
    int*   flags  = (int*)carve(16);
    int*   counts = (int*)carve(110000 * 4);
    int*   offs   = (int*)carve(110003 * 4);
    int*   cursor = (int*)carve(110000 * 4);
    int*   bsums  = (int*)carve(192 * 4);
    float* Wc     = (float*)carve(16384 * 4);
    int*   bcur   = (int*)carve(3 * NBK * 4);
    int*   vals   = (int*)carve(2400000 * 4);
    // union block: staging pairs (19.2MB, dead after unbin) overlaps P+MH+XH (28.16MB)
    char*  U      = carve((size_t)NN * 128 * 2 + (size_t)HECNT * 128 * 2 + (size_t)NN * 128 * 2);
    _Float16* P  = (_Float16*)U;
    _Float16* MH = (_Float16*)(U + (size_t)NN * 128 * 2);
    _Float16* XH = (_Float16*)(U + (size_t)NN * 128 * 2 + (size_t)HECNT * 128 * 2);
    uint2*    pairs = (uint2*)U;
    bool fast = (off <= ws_size);   // staged sort + f16 shadow need the full carve

    float* XO = (float*)d_out;                 // final X: 50000 x 128 f32 (activation chain, in-place)
    float* YO = XO + (size_t)NN * 128;         // final y: 50000 x 64 f32

    // ---- CSR build ----
    hipMemsetAsync(counts, 0, 110000 * 4, stream);
    detect_k<<<1, 256, 0, stream>>>(EIX, HIX, flags);
    hist_k<<<dim3(3125, 3), 256, 0, stream>>>(EIX, HIX, flags, counts);
    scan_p1<<<dim3(49, 3), 256, 0, stream>>>(counts, bsums);
    scan_p2<<<dim3(1, 3), 64, 0, stream>>>(bsums, offs);
    scan_p3<<<dim3(49, 3), 256, 0, stream>>>(counts, bsums, offs, cursor);
    if (fast) {
        binit_k<<<2, 256, 0, stream>>>(offs, bcur);
        bin_k<<<dim3((EE + CHUNK - 1) / CHUNK, 3), 256, 0, stream>>>(EIX, HIX, flags, bcur, pairs);
        unbin_k<<<3 * NBK, 256, 0, stream>>>(offs, pairs, vals);
    } else {
        fill_k<<<dim3(3125, 3), 256, 0, stream>>>(EIX, HIX, flags, cursor, vals);
    }

    const int* offs_he   = offs;                    // [HECNT+1]
    const int* offs_node = offs + HECNT + 1;        // [NN+1]
    const int* offs_dst  = offs + HECNT + NN + 2;   // [NN+1]
    const int* vals_he   = vals;
    const int* vals_node = vals + 800000;
    const int* vals_dst  = vals + 1600000;

    int gg  = (NN + 127) / 128;       // 391
    int ghe = (HECNT + 3) / 4;        // 2500
    int gnn = (NN + 3) / 4;           // 12500
    _Float16* xh = fast ? XH : nullptr;

    // ---- Layer 1: X1 = leaky(HGC(X) + X@lin1 + lin1_b) ----
    gemm_k<128, float, _Float16><<<gg, 256, 0, stream>>>(X, hc1_w, nullptr, nullptr, nullptr, P, nullptr, NN, 0);
    gather_k<_Float16><<<ghe, 256, 0, stream>>>(offs_he, vals_he, P, MH, HECNT, NN, 1, nullptr, 0);
    gather_k<_Float16><<<gnn, 256, 0, stream>>>(offs_node, vals_node, MH, P, NN, HECNT, 1, hc1_b, 0);
    gemm_k<128, float, float><<<gg, 256, 0, stream>>>(X, lin1_w, lin1_b, nullptr, P, XO, nullptr, NN, 1);

    // ---- Layer 2 ----
    gemm_k<128, float, _Float16><<<gg, 256, 0, stream>>>(XO, hc2_w, nullptr, nullptr, nullptr, P, nullptr, NN, 0);
    gather_k<_Float16><<<ghe, 256, 0, stream>>>(offs_he, vals_he, P, MH, HECNT, NN, 1, nullptr, 0);
    gather_k<_Float16><<<gnn, 256, 0, stream>>>(offs_node, vals_node, MH, P, NN, HECNT, 1, hc2_b, 0);
    gemm_k<128, float, float><<<gg, 256, 0, stream>>>(XO, lin2_w, lin2_b, nullptr, P, XO, xh, NN, 1);  // + f16 shadow X2

    // ---- Layer 3: X3 = leaky(AGG@Wrel + brel + X2@(Wroot+glin1_w) + glin1_b) ----
    wadd_k<<<64, 256, 0, stream>>>(c1_wroot, glin1_w, Wc);
    if (fast) gather_k<_Float16><<<gnn, 256, 0, stream>>>(offs_dst, vals_dst, XH, P, NN, NN, 0, nullptr, 0);
    else      gather_k<float><<<gnn, 256, 0, stream>>>(offs_dst, vals_dst, XO, P, NN, NN, 0, nullptr, 0);
    gemm_k<128, _Float16, _Float16><<<gg, 256, 0, stream>>>(P, c1_wrel, c1_brel, nullptr, nullptr, P, nullptr, NN, 0);
    gemm_k<128, float, float><<<gg, 256, 0, stream>>>(XO, Wc, glin1_b, nullptr, P, XO, xh, NN, 1);     // + f16 shadow X3

    // ---- Layer 4 ----
    wadd_k<<<64, 256, 0, stream>>>(c2_wroot, glin2_w, Wc);
    if (fast) gather_k<_Float16><<<gnn, 256, 0, stream>>>(offs_dst, vals_dst, XH, P, NN, NN, 0, nullptr, 0);
    else      gather_k<float><<<gnn, 256, 0, stream>>>(offs_dst, vals_dst, XO, P, NN, NN, 0, nullptr, 0);
    gemm_k<128, _Float16, _Float16><<<gg, 256, 0, stream>>>(P, c2_wrel, c2_brel, nullptr, nullptr, P, nullptr, NN, 0);
    gemm_k<128, float, float><<<gg, 256, 0, stream>>>(XO, Wc, glin2_b, nullptr, P, XO, nullptr, NN, 1); // XO final

    // ---- fc head ----
    gemm_k<64, float, float><<<gg, 256, 0, stream>>>(XO, fc_w, fc_b, nullptr, nullptr, YO, nullptr, NN, 0);
}

// Round 5
// 576.301 us; speedup vs baseline: 1.7530x; 1.5285x over previous
//
#include <hip/hip_runtime.h>

#define NN 50000
#define HECNT 10000
#define EE 800000
#define II 800000
#define NBK 128          // buckets per task (counting sort)
#define CHUNK 4096       // edges per workgroup in bin2_k
#define BKCAP 8192       // fixed staging capacity per bucket (mean 6250, +24 sigma)

typedef _Float16 h2    __attribute__((ext_vector_type(2)));
typedef _Float16 half8 __attribute__((ext_vector_type(8)));
typedef float f32x4    __attribute__((ext_vector_type(4)));

// ---------------- index-width detection ----------------
__global__ void detect_k(const int* __restrict__ EIX, const int* __restrict__ HIX,
                         int* __restrict__ flags) {
    __shared__ int o0, o1;
    int tid = threadIdx.x;
    if (tid == 0) { o0 = 0; o1 = 0; }
    __syncthreads();
    atomicOr(&o0, EIX[2 * tid + 1]);
    atomicOr(&o1, HIX[2 * tid + 1]);
    __syncthreads();
    if (tid == 0) { flags[0] = (o0 == 0); flags[1] = (o1 == 0); }
}

__device__ __forceinline__ int ld_idx(const int* p, long long pos, int is64) {
    return is64 ? p[pos * 2] : p[(int)pos];
}

__device__ __forceinline__ void task_info(int t, int& n, int& cbase, int& obase) {
    if (t == 0)      { n = HECNT; cbase = 0;           obase = 0; }
    else if (t == 1) { n = NN;    cbase = HECNT;       obase = HECNT + 1; }
    else             { n = NN;    cbase = HECNT + NN;  obase = HECNT + NN + 2; }
}

// load (dest, val) for incidence/edge i of task t; dest<0 if invalid
__device__ __forceinline__ void ld_edge(int t, long long i,
                                        const int* EIX, const int* HIX,
                                        int f0, int f1, int& d, int& v) {
    int rng;
    if (t == 0)      { d = ld_idx(HIX, (long long)II + i, f1); v = ld_idx(HIX, i, f1); rng = HECNT; }
    else if (t == 1) { d = ld_idx(HIX, i, f1); v = ld_idx(HIX, (long long)II + i, f1); rng = NN; }
    else             { d = ld_idx(EIX, (long long)EE + i, f0); v = ld_idx(EIX, i, f0); rng = NN; }
    if ((unsigned)d >= (unsigned)rng) d = -1;
}

// -------- fallback path (only if ws too small): global-atomic hist + fill --------
__global__ __launch_bounds__(256) void hist_k(const int* __restrict__ EIX,
                                              const int* __restrict__ HIX,
                                              const int* __restrict__ flags,
                                              int* __restrict__ counts) {
    int t = blockIdx.y;
    int i = blockIdx.x * 256 + threadIdx.x;
    if (i >= EE) return;
    int cb = (t == 0) ? 0 : (t == 1 ? HECNT : HECNT + NN);
    int d, v;
    ld_edge(t, i, EIX, HIX, flags[0], flags[1], d, v);
    if (d >= 0) atomicAdd(&counts[cb + d], 1);
}

__global__ __launch_bounds__(256) void fill_k(const int* __restrict__ EIX,
                                              const int* __restrict__ HIX,
                                              const int* __restrict__ flags,
                                              int* __restrict__ cursor,
                                              int* __restrict__ vals) {
    int t = blockIdx.y;
    int i = blockIdx.x * 256 + threadIdx.x;
    if (i >= EE) return;
    int cb = (t == 0) ? 0 : (t == 1 ? HECNT : HECNT + NN);
    int d, v;
    ld_edge(t, i, EIX, HIX, flags[0], flags[1], d, v);
    if (d < 0) return;
    int p = atomicAdd(&cursor[cb + d], 1);
    if ((unsigned)p < 800000u) vals[t * 800000 + p] = v;
}

// ---------------- fast path: bucket sort with fixed-capacity staging ----------------
__global__ void binit_k(int* __restrict__ bcur) {
    int i = blockIdx.x * 256 + threadIdx.x;
    if (i < 3 * NBK) bcur[i] = i * BKCAP;
}

__global__ __launch_bounds__(256) void bin_k(const int* __restrict__ EIX,
                                             const int* __restrict__ HIX,
                                             const int* __restrict__ flags,
                                             int* __restrict__ bcur,
                                             uint2* __restrict__ pairs) {
    int t = blockIdx.y;
    __shared__ int hcnt[NBK], hstart[NBK], hrun[NBK], gbase[NBK];
    __shared__ int stot;
    __shared__ uint2 stage[CHUNK];       // 32 KB
    int tid = threadIdx.x;
    int n, cb, ob; task_info(t, n, cb, ob);
    int span = (n + NBK - 1) / NBK;
    long long base = (long long)blockIdx.x * CHUNK;
    int f0 = flags[0], f1 = flags[1];

    for (int i = tid; i < NBK; i += 256) { hcnt[i] = 0; hrun[i] = 0; }
    __syncthreads();

    int d[16], v[16], b[16];
    #pragma unroll
    for (int j = 0; j < 16; j++) {
        long long i = base + j * 256 + tid;
        int dd = -1, vv = 0;
        if (i < EE) ld_edge(t, i, EIX, HIX, f0, f1, dd, vv);
        d[j] = dd; v[j] = vv;
        if (dd >= 0) { b[j] = dd / span; atomicAdd(&hcnt[b[j]], 1); }
    }
    __syncthreads();

    // reserve fixed-capacity staging runs
    if (tid < NBK) gbase[tid] = hcnt[tid] ? atomicAdd(&bcur[t * NBK + tid], hcnt[tid]) : 0;
    if (tid < NBK) hstart[tid] = hcnt[tid];
    __syncthreads();
    for (int o = 1; o < NBK; o <<= 1) {
        int u = 0;
        if (tid < NBK && tid >= o) u = hstart[tid - o];
        __syncthreads();
        if (tid < NBK) hstart[tid] += u;
        __syncthreads();
    }
    if (tid == NBK - 1) stot = hstart[tid];
    __syncthreads();
    if (tid < NBK) hstart[tid] -= hcnt[tid];   // exclusive
    __syncthreads();

    #pragma unroll
    for (int j = 0; j < 16; j++) {
        if (d[j] >= 0) {
            int p = hstart[b[j]] + atomicAdd(&hrun[b[j]], 1);
            stage[p] = make_uint2((unsigned)d[j], (unsigned)v[j]);
        }
    }
    __syncthreads();

    int total = stot;
    for (int i = tid; i < total; i += 256) {
        int lo = 0, hi = NBK - 1;                  // last bucket with hstart <= i
        while (lo < hi) { int mid = (lo + hi + 1) >> 1; if (hstart[mid] <= i) lo = mid; else hi = mid - 1; }
        int pos = gbase[lo] + (i - hstart[lo]);
        if (pos < (t * NBK + lo + 1) * BKCAP)      // capacity clamp (never expected)
            pairs[pos] = stage[i];
    }
}

// per-bucket dest histogram from staged pairs — LDS atomics only, coalesced writes
__global__ __launch_bounds__(256) void count_k(const int* __restrict__ bcur,
                                               const uint2* __restrict__ pairs,
                                               int* __restrict__ counts) {
    int idx = blockIdx.x;              // 0 .. 3*NBK-1
    int t = idx / NBK, b = idx % NBK;
    int n, cb, ob; task_info(t, n, cb, ob);
    int span = (n + NBK - 1) / NBK;
    int dlo = min(b * span, n), dhi = min(dlo + span, n);
    __shared__ int hist[400];
    int tid = threadIdx.x;
    for (int i = tid; i < dhi - dlo; i += 256) hist[i] = 0;
    __syncthreads();
    int cnt = min(bcur[idx] - idx * BKCAP, BKCAP);
    const uint2* pw = pairs + (size_t)idx * BKCAP;
    for (int i = tid; i < cnt; i += 256) {
        int dl = (int)pw[i].x - dlo;
        if ((unsigned)dl < (unsigned)(dhi - dlo)) atomicAdd(&hist[dl], 1);
    }
    __syncthreads();
    for (int i = tid; i < dhi - dlo; i += 256) counts[cb + dlo + i] = hist[i];
}

__global__ __launch_bounds__(256) void scan_p1(const int* __restrict__ counts,
                                               int* __restrict__ bsums) {
    int t = blockIdx.y;
    int n, cb, ob; task_info(t, n, cb, ob);
    int base = blockIdx.x * 1024 + threadIdx.x * 4;
    int s = 0;
    #pragma unroll
    for (int j = 0; j < 4; j++) { int i = base + j; if (i < n) s += counts[cb + i]; }
    __shared__ int red[256];
    red[threadIdx.x] = s; __syncthreads();
    for (int o = 128; o > 0; o >>= 1) {
        if (threadIdx.x < o) red[threadIdx.x] += red[threadIdx.x + o];
        __syncthreads();
    }
    if (threadIdx.x == 0) bsums[t * 64 + blockIdx.x] = red[0];
}

__global__ void scan_p2(int* __restrict__ bsums, int* __restrict__ offs) {
    int t = blockIdx.y;
    int n, cb, ob; task_info(t, n, cb, ob);
    int lane = threadIdx.x;
    int nb = (n + 1023) / 1024;
    int v = (lane < nb) ? bsums[t * 64 + lane] : 0;
    int incl = v;
    for (int d = 1; d < 64; d <<= 1) {
        int u = __shfl_up(incl, (unsigned)d, 64);
        if (lane >= d) incl += u;
    }
    bsums[t * 64 + lane] = incl - v;           // exclusive block sums
    int total = __shfl(incl, 63, 64);
    if (lane == 0) offs[ob + n] = total;
}

__global__ __launch_bounds__(256) void scan_p3(const int* __restrict__ counts,
                                               const int* __restrict__ bsums,
                                               int* __restrict__ offs,
                                               int* __restrict__ cursor) {
    int t = blockIdx.y;
    int n, cb, ob; task_info(t, n, cb, ob);
    int tid = threadIdx.x;
    int base = blockIdx.x * 1024 + tid * 4;
    int c[4]; int s = 0;
    #pragma unroll
    for (int j = 0; j < 4; j++) { int i = base + j; c[j] = (i < n) ? counts[cb + i] : 0; s += c[j]; }
    __shared__ int sc[256];
    sc[tid] = s; __syncthreads();
    for (int o = 1; o < 256; o <<= 1) {
        int v = (tid >= o) ? sc[tid - o] : 0;
        __syncthreads();
        sc[tid] += v;
        __syncthreads();
    }
    int excl = sc[tid] - s;
    int p = bsums[t * 64 + blockIdx.x] + excl;
    #pragma unroll
    for (int j = 0; j < 4; j++) {
        int i = base + j;
        if (i < n) { offs[ob + i] = p; cursor[cb + i] = p; p += c[j]; }
    }
}

// per-bucket exact CSR placement via LDS window, coalesced flush
__global__ __launch_bounds__(256) void unbin_k(const int* __restrict__ offs,
                                               const uint2* __restrict__ pairs,
                                               int* __restrict__ vals) {
    int idx = blockIdx.x;              // 0 .. 3*NBK-1
    int t = idx / NBK, b = idx % NBK;
    int n, cb, ob; task_info(t, n, cb, ob);
    int span = (n + NBK - 1) / NBK;
    int dlo = min(b * span, n), dhi = min(dlo + span, n);
    if (dhi <= dlo) return;
    int p0 = offs[ob + dlo], p1 = offs[ob + dhi];
    int cnt = p1 - p0;                 // == staged count (counts derived from staging)
    __shared__ int win[BKCAP];         // 32 KB
    __shared__ int cur[400];
    int tid = threadIdx.x;
    for (int i = tid; i < dhi - dlo; i += 256) cur[i] = offs[ob + dlo + i] - p0;
    __syncthreads();
    const uint2* pw = pairs + (size_t)idx * BKCAP;
    int* vw = vals + (size_t)t * 800000 + p0;
    if (cnt > BKCAP) cnt = BKCAP;
    for (int i = tid; i < cnt; i += 256) {
        uint2 pv = pw[i];
        int dl = (int)pv.x - dlo;
        if ((unsigned)dl < (unsigned)(dhi - dlo)) {
            int p = atomicAdd(&cur[dl], 1);
            if ((unsigned)p < (unsigned)BKCAP) win[p] = (int)pv.y;
        }
    }
    __syncthreads();
    for (int i = tid; i < cnt; i += 256) vw[i] = win[i];
}

// ------- gather: 1 dest/wave, 16 lanes x half8 per row, 4 edges in flight, xor-reduce -------
template <typename ST>
__global__ __launch_bounds__(256) void gather_k(const int* __restrict__ offs,
                                                const int* __restrict__ vals,
                                                const ST* __restrict__ src,     // [S x 128]
                                                _Float16* __restrict__ out,     // [ndst x 128]
                                                int ndst, int nsrc, int scale_flag,
                                                const float* __restrict__ bias,
                                                int act) {
    int wave = threadIdx.x >> 6, lane = threadIdx.x & 63;
    int sub = lane >> 4, l16 = lane & 15;
    int d = blockIdx.x * 4 + wave;
    if (d >= ndst) return;
    int beg = offs[d], end = offs[d + 1];
    int f = l16 * 8;
    float a[8] = {0.f, 0.f, 0.f, 0.f, 0.f, 0.f, 0.f, 0.f};
    auto acc_row = [&](int s) {
        if ((unsigned)s < (unsigned)nsrc) {
            if constexpr (sizeof(ST) == 2) {
                half8 u = *(const half8*)(src + (size_t)s * 128 + f);
                #pragma unroll
                for (int j = 0; j < 8; j++) a[j] += (float)u[j];
            } else {
                const float* rp = (const float*)src + (size_t)s * 128 + f;
                f32x4 x0 = *(const f32x4*)rp;
                f32x4 x1 = *(const f32x4*)(rp + 4);
                #pragma unroll
                for (int j = 0; j < 4; j++) { a[j] += x0[j]; a[4 + j] += x1[j]; }
            }
        }
    };
    int e = beg + sub;
    for (; e + 4 < end; e += 8) {            // 2 rows in flight per lane, 8 per wave
        int s0 = vals[e], s1 = vals[e + 4];
        acc_row(s0); acc_row(s1);
    }
    if (e < end) acc_row(vals[e]);
    // combine partial sums across the 4 sub-groups
    #pragma unroll
    for (int j = 0; j < 8; j++) {
        a[j] += __shfl_xor(a[j], 16, 64);
        a[j] += __shfl_xor(a[j], 32, 64);
    }
    if (sub == 0) {
        if (scale_flag) {
            int c = end - beg;
            float iv = (c > 0) ? 1.f / (float)c : 0.f;
            #pragma unroll
            for (int j = 0; j < 8; j++) a[j] *= iv;
        }
        if (bias) {
            f32x4 b0 = *(const f32x4*)(bias + f);
            f32x4 b1 = *(const f32x4*)(bias + f + 4);
            #pragma unroll
            for (int j = 0; j < 4; j++) { a[j] += b0[j]; a[4 + j] += b1[j]; }
        }
        if (act) {
            #pragma unroll
            for (int j = 0; j < 8; j++) a[j] = (a[j] >= 0.f) ? a[j] : 0.01f * a[j];
        }
        half8 o;
        #pragma unroll
        for (int j = 0; j < 8; j++) o[j] = (_Float16)a[j];
        *(half8*)(out + (size_t)d * 128 + f) = o;
    }
}

// ---- MFMA GEMM (f16 matrix cores, f32 accumulate); A==C in-place safe:
//      C[MxN] = act(A[Mx128] @ W[128xN] + bias + bias2 + addend); optional f16 shadow C2
template <int N, typename AT, typename CT>
__global__ __launch_bounds__(256) void gemm_k(const AT* A,
                                              const float* __restrict__ W,    // [128 x N]
                                              const float* __restrict__ bias,
                                              const float* __restrict__ bias2,
                                              const _Float16* addend,          // [M x N]
                                              CT* C,
                                              _Float16* C2,
                                              int M, int act) {
    constexpr int K = 128;
    constexpr int LDT = K + 8;
    constexpr int NT = N / 16;
    __shared__ _Float16 Wt[N * LDT];
    int tid = threadIdx.x;
    for (int idx = tid; idx < K * N; idx += 256) {
        int k = idx / N, n = idx % N;
        Wt[n * LDT + k] = (_Float16)W[idx];
    }
    __syncthreads();

    int wave = tid >> 6, lane = tid & 63;
    int quad = lane >> 4, l16 = lane & 15;
    int rowbase = blockIdx.x * 128 + wave * 32;

    f32x4 acc[2][NT];
    f32x4 zero4 = {0.f, 0.f, 0.f, 0.f};
    #pragma unroll
    for (int mt = 0; mt < 2; mt++)
        #pragma unroll
        for (int nt = 0; nt < NT; nt++) acc[mt][nt] = zero4;

    #pragma unroll
    for (int ks = 0; ks < 4; ks++) {
        int k0 = ks * 32 + quad * 8;
        half8 af[2];
        #pragma unroll
        for (int mt = 0; mt < 2; mt++) {
            int row = rowbase + mt * 16 + l16;
            half8 v = {0, 0, 0, 0, 0, 0, 0, 0};
            if (row < M) {
                if constexpr (sizeof(AT) == 4) {
                    const float* ap = (const float*)A + (size_t)row * K + k0;
                    float4 x0 = *(const float4*)ap;
                    float4 x1 = *(const float4*)(ap + 4);
                    v = half8{(_Float16)x0.x, (_Float16)x0.y, (_Float16)x0.z, (_Float16)x0.w,
                              (_Float16)x1.x, (_Float16)x1.y, (_Float16)x1.z, (_Float16)x1.w};
                } else {
                    v = *(const half8*)((const _Float16*)A + (size_t)row * K + k0);
                }
            }
            af[mt] = v;
        }
        #pragma unroll
        for (int nt = 0; nt < NT; nt++) {
            half8 bfr = *(const half8*)(&Wt[(nt * 16 + l16) * LDT + k0]);
            #pragma unroll
            for (int mt = 0; mt < 2; mt++)
                acc[mt][nt] = __builtin_amdgcn_mfma_f32_16x16x32_f16(af[mt], bfr, acc[mt][nt], 0, 0, 0);
        }
    }

    #pragma unroll
    for (int nt = 0; nt < NT; nt++) {
        int col = nt * 16 + l16;
        float bv = 0.f;
        if (bias)  bv += bias[col];
        if (bias2) bv += bias2[col];
        #pragma unroll
        for (int mt = 0; mt < 2; mt++) {
            #pragma unroll
            for (int r = 0; r < 4; r++) {
                int row = rowbase + mt * 16 + quad * 4 + r;
                if (row < M) {
                    float v = acc[mt][nt][r] + bv;
                    if (addend) v += (float)addend[(size_t)row * N + col];
                    if (act) v = (v >= 0.f) ? v : 0.01f * v;
                    C[(size_t)row * N + col] = (CT)v;
                    if (C2) C2[(size_t)row * N + col] = (_Float16)v;
                }
            }
        }
    }
}

__global__ __launch_bounds__(256) void wadd_k(const float* __restrict__ a,
                                              const float* __restrict__ b,
                                              float* __restrict__ o) {
    int i = blockIdx.x * 256 + threadIdx.x;
    if (i < 16384) o[i] = a[i] + b[i];
}

extern "C" void kernel_launch(void* const* d_in, const int* in_sizes, int n_in,
                              void* d_out, int out_size, void* d_ws, size_t ws_size,
                              hipStream_t stream) {
    const float* X       = (const float*)d_in[0];
    const int*   EIX     = (const int*)d_in[1];
    const int*   HIX     = (const int*)d_in[2];
    const float* hc1_w   = (const float*)d_in[3];
    const float* hc1_b   = (const float*)d_in[4];
    const float* lin1_w  = (const float*)d_in[5];
    const float* lin1_b  = (const float*)d_in[6];
    const float* hc2_w   = (const float*)d_in[7];
    const float* hc2_b   = (const float*)d_in[8];
    const float* lin2_w  = (const float*)d_in[9];
    const float* lin2_b  = (const float*)d_in[10];
    const float* c1_wrel = (const float*)d_in[11];
    const float* c1_brel = (const float*)d_in[12];
    const float* c1_wroot= (const float*)d_in[13];
    const float* glin1_w = (const float*)d_in[14];
    const float* glin1_b = (const float*)d_in[15];
    const float* c2_wrel = (const float*)d_in[16];
    const float* c2_brel = (const float*)d_in[17];
    const float* c2_wroot= (const float*)d_in[18];
    const float* glin2_w = (const float*)d_in[19];
    const float* glin2_b = (const float*)d_in[20];
    const float* fc_w    = (const float*)d_in[21];
    const float* fc_b    = (const float*)d_in[22];

    // ---- workspace carve ----
    char* wsp = (char*)d_ws;
    size_t off = 0;
    auto carve = [&](size_t bytes) -> char* {
        char* p = wsp + off;
        off = (off + bytes + 255) & ~(size_t)255;
        return p;
    };
    int*   flags  = (int*)carve(16);
    int*   counts = (int*)carve(110000 * 4);
    int*   offs   = (int*)carve(110003 * 4);
    int*   cursor = (int*)carve(110000 * 4);
    int*   bsums  = (int*)carve(192 * 4);
    float* Wc     = (float*)carve(16384 * 4);
    int*   bcur   = (int*)carve(3 * NBK * 4);
    int*   vals   = (int*)carve(2400000 * 4);
    // union: staging pairs (3*NBK*BKCAP*8 = 25.2MB, dead after unbin) vs P+MH+XH (28.16MB)
    size_t ubytes = (size_t)NN * 128 * 2 + (size_t)HECNT * 128 * 2 + (size_t)NN * 128 * 2;
    char*  U      = carve(ubytes);
    _Float16* P  = (_Float16*)U;
    _Float16* MH = (_Float16*)(U + (size_t)NN * 128 * 2);
    _Float16* XH = (_Float16*)(U + (size_t)NN * 128 * 2 + (size_t)HECNT * 128 * 2);
    uint2*    pairs = (uint2*)U;
    bool fast = (off <= ws_size);

    float* XO = (float*)d_out;                 // final X: 50000 x 128 f32 (in-place chain)
    float* YO = XO + (size_t)NN * 128;         // final y: 50000 x 64 f32

    // ---- CSR build ----
    detect_k<<<1, 256, 0, stream>>>(EIX, HIX, flags);
    if (fast) {
        binit_k<<<2, 256, 0, stream>>>(bcur);
        bin_k<<<dim3((EE + CHUNK - 1) / CHUNK, 3), 256, 0, stream>>>(EIX, HIX, flags, bcur, pairs);
        count_k<<<3 * NBK, 256, 0, stream>>>(bcur, pairs, counts);
        scan_p1<<<dim3(49, 3), 256, 0, stream>>>(counts, bsums);
        scan_p2<<<dim3(1, 3), 64, 0, stream>>>(bsums, offs);
        scan_p3<<<dim3(49, 3), 256, 0, stream>>>(counts, bsums, offs, cursor);
        unbin_k<<<3 * NBK, 256, 0, stream>>>(offs, pairs, vals);
    } else {
        hipMemsetAsync(counts, 0, 110000 * 4, stream);
        hist_k<<<dim3(3125, 3), 256, 0, stream>>>(EIX, HIX, flags, counts);
        scan_p1<<<dim3(49, 3), 256, 0, stream>>>(counts, bsums);
        scan_p2<<<dim3(1, 3), 64, 0, stream>>>(bsums, offs);
        scan_p3<<<dim3(49, 3), 256, 0, stream>>>(counts, bsums, offs, cursor);
        fill_k<<<dim3(3125, 3), 256, 0, stream>>>(EIX, HIX, flags, cursor, vals);
    }

    const int* offs_he   = offs;                    // [HECNT+1]
    const int* offs_node = offs + HECNT + 1;        // [NN+1]
    const int* offs_dst  = offs + HECNT + NN + 2;   // [NN+1]
    const int* vals_he   = vals;
    const int* vals_node = vals + 800000;
    const int* vals_dst  = vals + 1600000;

    int gg  = (NN + 127) / 128;       // 391
    int ghe = (HECNT + 3) / 4;        // 2500
    int gnn = (NN + 3) / 4;           // 12500
    _Float16* xh = fast ? XH : nullptr;

    // ---- Layer 1: X1 = leaky(HGC(X) + X@lin1 + lin1_b) ----
    gemm_k<128, float, _Float16><<<gg, 256, 0, stream>>>(X, hc1_w, nullptr, nullptr, nullptr, P, nullptr, NN, 0);
    gather_k<_Float16><<<ghe, 256, 0, stream>>>(offs_he, vals_he, P, MH, HECNT, NN, 1, nullptr, 0);
    gather_k<_Float16><<<gnn, 256, 0, stream>>>(offs_node, vals_node, MH, P, NN, HECNT, 1, hc1_b, 0);
    gemm_k<128, float, float><<<gg, 256, 0, stream>>>(X, lin1_w, lin1_b, nullptr, P, XO, nullptr, NN, 1);

    // ---- Layer 2 ----
    gemm_k<128, float, _Float16><<<gg, 256, 0, stream>>>(XO, hc2_w, nullptr, nullptr, nullptr, P, nullptr, NN, 0);
    gather_k<_Float16><<<ghe, 256, 0, stream>>>(offs_he, vals_he, P, MH, HECNT, NN, 1, nullptr, 0);
    gather_k<_Float16><<<gnn, 256, 0, stream>>>(offs_node, vals_node, MH, P, NN, HECNT, 1, hc2_b, 0);
    gemm_k<128, float, float><<<gg, 256, 0, stream>>>(XO, lin2_w, lin2_b, nullptr, P, XO, xh, NN, 1);  // + f16 shadow

    // ---- Layer 3: X3 = leaky(AGG@Wrel + brel + X2@(Wroot+glin1_w) + glin1_b) ----
    wadd_k<<<64, 256, 0, stream>>>(c1_wroot, glin1_w, Wc);
    if (fast) gather_k<_Float16><<<gnn, 256, 0, stream>>>(offs_dst, vals_dst, XH, P, NN, NN, 0, nullptr, 0);
    else      gather_k<float><<<gnn, 256, 0, stream>>>(offs_dst, vals_dst, XO, P, NN, NN, 0, nullptr, 0);
    gemm_k<128, _Float16, _Float16><<<gg, 256, 0, stream>>>(P, c1_wrel, c1_brel, nullptr, nullptr, P, nullptr, NN, 0);
    gemm_k<128, float, float><<<gg, 256, 0, stream>>>(XO, Wc, glin1_b, nullptr, P, XO, xh, NN, 1);     // + f16 shadow

    // ---- Layer 4 ----
    wadd_k<<<64, 256, 0, stream>>>(c2_wroot, glin2_w, Wc);
    if (fast) gather_k<_Float16><<<gnn, 256, 0, stream>>>(offs_dst, vals_dst, XH, P, NN, NN, 0, nullptr, 0);
    else      gather_k<float><<<gnn, 256, 0, stream>>>(offs_dst, vals_dst, XO, P, NN, NN, 0, nullptr, 0);
    gemm_k<128, _Float16, _Float16><<<gg, 256, 0, stream>>>(P, c2_wrel, c2_brel, nullptr, nullptr, P, nullptr, NN, 0);
    gemm_k<128, float, float><<<gg, 256, 0, stream>>>(XO, Wc, glin2_b, nullptr, P, XO, nullptr, NN, 1); // XO final

    // ---- fc head ----
    gemm_k<64, float, float><<<gg, 256, 0, stream>>>(XO, fc_w, fc_b, nullptr, nullptr, YO, nullptr, NN, 0);
}

// Round 6
// 551.914 us; speedup vs baseline: 1.8305x; 1.0442x over previous
//
#include <hip/hip_runtime.h>

#define NN 50000
#define HECNT 10000
#define EE 800000
#define II 800000
#define NBK 128          // buckets per task (counting sort)
#define CHUNK 4096       // edges per workgroup in bin_k
#define BKCAP 8192       // fixed staging capacity per bucket (mean 6250, +24 sigma)

typedef _Float16 half8 __attribute__((ext_vector_type(8)));
typedef float f32x4    __attribute__((ext_vector_type(4)));

// ---------------- index-width detection ----------------
__global__ void detect_k(const int* __restrict__ EIX, const int* __restrict__ HIX,
                         int* __restrict__ flags) {
    __shared__ int o0, o1;
    int tid = threadIdx.x;
    if (tid == 0) { o0 = 0; o1 = 0; }
    __syncthreads();
    atomicOr(&o0, EIX[2 * tid + 1]);
    atomicOr(&o1, HIX[2 * tid + 1]);
    __syncthreads();
    if (tid == 0) { flags[0] = (o0 == 0); flags[1] = (o1 == 0); }
}

__device__ __forceinline__ int ld_idx(const int* p, long long pos, int is64) {
    return is64 ? p[pos * 2] : p[(int)pos];
}

__device__ __forceinline__ void task_info(int t, int& n, int& cbase, int& obase) {
    if (t == 0)      { n = HECNT; cbase = 0;           obase = 0; }
    else if (t == 1) { n = NN;    cbase = HECNT;       obase = HECNT + 1; }
    else             { n = NN;    cbase = HECNT + NN;  obase = HECNT + NN + 2; }
}

// load (dest, val) for incidence/edge i of task t; dest<0 if invalid
__device__ __forceinline__ void ld_edge(int t, long long i,
                                        const int* EIX, const int* HIX,
                                        int f0, int f1, int& d, int& v) {
    int rng;
    if (t == 0)      { d = ld_idx(HIX, (long long)II + i, f1); v = ld_idx(HIX, i, f1); rng = HECNT; }
    else if (t == 1) { d = ld_idx(HIX, i, f1); v = ld_idx(HIX, (long long)II + i, f1); rng = NN; }
    else             { d = ld_idx(EIX, (long long)EE + i, f0); v = ld_idx(EIX, i, f0); rng = NN; }
    if ((unsigned)d >= (unsigned)rng || (unsigned)v >= 65536u) d = -1;
}

// ---------------- bucket sort with fixed-capacity staging, packed u32 pairs ----------------
__global__ void binit_k(int* __restrict__ bcur) {
    int i = blockIdx.x * 256 + threadIdx.x;
    if (i < 3 * NBK) bcur[i] = i * BKCAP;
}

__global__ __launch_bounds__(256) void bin_k(const int* __restrict__ EIX,
                                             const int* __restrict__ HIX,
                                             const int* __restrict__ flags,
                                             int* __restrict__ bcur,
                                             unsigned* __restrict__ pairs) {
    int t = blockIdx.y;
    __shared__ int hcnt[NBK], hstart[NBK], hrun[NBK], gbase[NBK];
    __shared__ int stot;
    __shared__ unsigned stage[CHUNK];    // 16 KB
    int tid = threadIdx.x;
    int n, cb, ob; task_info(t, n, cb, ob);
    int span = (n + NBK - 1) / NBK;
    long long base = (long long)blockIdx.x * CHUNK;
    int f0 = flags[0], f1 = flags[1];

    for (int i = tid; i < NBK; i += 256) { hcnt[i] = 0; hrun[i] = 0; }
    __syncthreads();

    int d[16], v[16], b[16];
    #pragma unroll
    for (int j = 0; j < 16; j++) {
        long long i = base + j * 256 + tid;
        int dd = -1, vv = 0;
        if (i < EE) ld_edge(t, i, EIX, HIX, f0, f1, dd, vv);
        d[j] = dd; v[j] = vv;
        if (dd >= 0) { b[j] = dd / span; atomicAdd(&hcnt[b[j]], 1); }
    }
    __syncthreads();

    if (tid < NBK) gbase[tid] = hcnt[tid] ? atomicAdd(&bcur[t * NBK + tid], hcnt[tid]) : 0;
    if (tid < NBK) hstart[tid] = hcnt[tid];
    __syncthreads();
    for (int o = 1; o < NBK; o <<= 1) {
        int u = 0;
        if (tid < NBK && tid >= o) u = hstart[tid - o];
        __syncthreads();
        if (tid < NBK) hstart[tid] += u;
        __syncthreads();
    }
    if (tid == NBK - 1) stot = hstart[tid];
    __syncthreads();
    if (tid < NBK) hstart[tid] -= hcnt[tid];   // exclusive
    __syncthreads();

    #pragma unroll
    for (int j = 0; j < 16; j++) {
        if (d[j] >= 0) {
            int p = hstart[b[j]] + atomicAdd(&hrun[b[j]], 1);
            stage[p] = ((unsigned)d[j] << 16) | (unsigned)v[j];
        }
    }
    __syncthreads();

    int total = stot;
    for (int i = tid; i < total; i += 256) {
        int lo = 0, hi = NBK - 1;                  // last bucket with hstart <= i
        while (lo < hi) { int mid = (lo + hi + 1) >> 1; if (hstart[mid] <= i) lo = mid; else hi = mid - 1; }
        int pos = gbase[lo] + (i - hstart[lo]);
        if (pos < (t * NBK + lo + 1) * BKCAP)      // capacity clamp (never expected)
            pairs[pos] = stage[i];
    }
}

// per-bucket dest histogram from staged pairs — LDS atomics only, coalesced writes
__global__ __launch_bounds__(256) void count_k(const int* __restrict__ bcur,
                                               const unsigned* __restrict__ pairs,
                                               int* __restrict__ counts) {
    int idx = blockIdx.x;              // 0 .. 3*NBK-1
    int t = idx / NBK, b = idx % NBK;
    int n, cb, ob; task_info(t, n, cb, ob);
    int span = (n + NBK - 1) / NBK;
    int dlo = min(b * span, n), dhi = min(dlo + span, n);
    __shared__ int hist[400];
    int tid = threadIdx.x;
    for (int i = tid; i < dhi - dlo; i += 256) hist[i] = 0;
    __syncthreads();
    int cnt = min(bcur[idx] - idx * BKCAP, BKCAP);
    const unsigned* pw = pairs + (size_t)idx * BKCAP;
    for (int i = tid; i < cnt; i += 256) {
        int dl = (int)(pw[i] >> 16) - dlo;
        if ((unsigned)dl < (unsigned)(dhi - dlo)) atomicAdd(&hist[dl], 1);
    }
    __syncthreads();
    for (int i = tid; i < dhi - dlo; i += 256) counts[cb + dlo + i] = hist[i];
}

__global__ __launch_bounds__(256) void scan_p1(const int* __restrict__ counts,
                                               int* __restrict__ bsums) {
    int t = blockIdx.y;
    int n, cb, ob; task_info(t, n, cb, ob);
    int base = blockIdx.x * 1024 + threadIdx.x * 4;
    int s = 0;
    #pragma unroll
    for (int j = 0; j < 4; j++) { int i = base + j; if (i < n) s += counts[cb + i]; }
    __shared__ int red[256];
    red[threadIdx.x] = s; __syncthreads();
    for (int o = 128; o > 0; o >>= 1) {
        if (threadIdx.x < o) red[threadIdx.x] += red[threadIdx.x + o];
        __syncthreads();
    }
    if (threadIdx.x == 0) bsums[t * 64 + blockIdx.x] = red[0];
}

__global__ void scan_p2(int* __restrict__ bsums, int* __restrict__ offs) {
    int t = blockIdx.y;
    int n, cb, ob; task_info(t, n, cb, ob);
    int lane = threadIdx.x;
    int nb = (n + 1023) / 1024;
    int v = (lane < nb) ? bsums[t * 64 + lane] : 0;
    int incl = v;
    for (int d = 1; d < 64; d <<= 1) {
        int u = __shfl_up(incl, (unsigned)d, 64);
        if (lane >= d) incl += u;
    }
    bsums[t * 64 + lane] = incl - v;           // exclusive block sums
    int total = __shfl(incl, 63, 64);
    if (lane == 0) offs[ob + n] = total;
}

__global__ __launch_bounds__(256) void scan_p3(const int* __restrict__ counts,
                                               const int* __restrict__ bsums,
                                               int* __restrict__ offs) {
    int t = blockIdx.y;
    int n, cb, ob; task_info(t, n, cb, ob);
    int tid = threadIdx.x;
    int base = blockIdx.x * 1024 + tid * 4;
    int c[4]; int s = 0;
    #pragma unroll
    for (int j = 0; j < 4; j++) { int i = base + j; c[j] = (i < n) ? counts[cb + i] : 0; s += c[j]; }
    __shared__ int sc[256];
    sc[tid] = s; __syncthreads();
    for (int o = 1; o < 256; o <<= 1) {
        int v = (tid >= o) ? sc[tid - o] : 0;
        __syncthreads();
        sc[tid] += v;
        __syncthreads();
    }
    int excl = sc[tid] - s;
    int p = bsums[t * 64 + blockIdx.x] + excl;
    #pragma unroll
    for (int j = 0; j < 4; j++) {
        int i = base + j;
        if (i < n) { offs[ob + i] = p; p += c[j]; }
    }
}

// per-bucket exact CSR placement via LDS window, coalesced flush
__global__ __launch_bounds__(256) void unbin_k(const int* __restrict__ offs,
                                               const unsigned* __restrict__ pairs,
                                               int* __restrict__ vals) {
    int idx = blockIdx.x;              // 0 .. 3*NBK-1
    int t = idx / NBK, b = idx % NBK;
    int n, cb, ob; task_info(t, n, cb, ob);
    int span = (n + NBK - 1) / NBK;
    int dlo = min(b * span, n), dhi = min(dlo + span, n);
    if (dhi <= dlo) return;
    int p0 = offs[ob + dlo], p1 = offs[ob + dhi];
    int cnt = p1 - p0;                 // == staged count (counts derived from staging)
    __shared__ int win[BKCAP];         // 32 KB
    __shared__ int cur[400];
    int tid = threadIdx.x;
    for (int i = tid; i < dhi - dlo; i += 256) cur[i] = offs[ob + dlo + i] - p0;
    __syncthreads();
    const unsigned* pw = pairs + (size_t)idx * BKCAP;
    int* vw = vals + (size_t)t * 800000 + p0;
    if (cnt > BKCAP) cnt = BKCAP;
    for (int i = tid; i < cnt; i += 256) {
        unsigned pv = pw[i];
        int dl = (int)(pv >> 16) - dlo;
        if ((unsigned)dl < (unsigned)(dhi - dlo)) {
            int p = atomicAdd(&cur[dl], 1);
            if ((unsigned)p < (unsigned)BKCAP) win[p] = (int)(pv & 0xffffu);
        }
    }
    __syncthreads();
    for (int i = tid; i < cnt; i += 256) vw[i] = win[i];
}

// ------- gather: 1 dest/wave, 16 lanes x half8, 4 edges in flight; epilogue finishes the layer -------
__global__ __launch_bounds__(256) void gather_k(const int* __restrict__ offs,
                                                const int* __restrict__ vals,
                                                const _Float16* __restrict__ src,   // [S x 128] f16
                                                _Float16* __restrict__ out,         // [ndst x 128] f16
                                                int ndst, int nsrc, int scale_flag,
                                                const float* __restrict__ bias,
                                                const _Float16* __restrict__ addend,
                                                int act) {
    int wave = threadIdx.x >> 6, lane = threadIdx.x & 63;
    int sub = lane >> 4, l16 = lane & 15;
    int d = blockIdx.x * 4 + wave;
    if (d >= ndst) return;
    int beg = offs[d], end = offs[d + 1];
    int f = l16 * 8;
    float a[8] = {0.f, 0.f, 0.f, 0.f, 0.f, 0.f, 0.f, 0.f};
    auto acc_row = [&](int s) {
        if ((unsigned)s < (unsigned)nsrc) {
            half8 u = *(const half8*)(src + (size_t)s * 128 + f);
            #pragma unroll
            for (int j = 0; j < 8; j++) a[j] += (float)u[j];
        }
    };
    int e = beg + sub;
    for (; e + 4 < end; e += 8) {            // 8 rows in flight per wave
        int s0 = vals[e], s1 = vals[e + 4];
        acc_row(s0); acc_row(s1);
    }
    if (e < end) acc_row(vals[e]);
    #pragma unroll
    for (int j = 0; j < 8; j++) {
        a[j] += __shfl_xor(a[j], 16, 64);
        a[j] += __shfl_xor(a[j], 32, 64);
    }
    if (sub == 0) {
        if (scale_flag) {
            int c = end - beg;
            float iv = (c > 0) ? 1.f / (float)c : 0.f;
            #pragma unroll
            for (int j = 0; j < 8; j++) a[j] *= iv;
        }
        if (bias) {
            f32x4 b0 = *(const f32x4*)(bias + f);
            f32x4 b1 = *(const f32x4*)(bias + f + 4);
            #pragma unroll
            for (int j = 0; j < 4; j++) { a[j] += b0[j]; a[4 + j] += b1[j]; }
        }
        if (addend) {
            half8 u = *(const half8*)(addend + (size_t)d * 128 + f);
            #pragma unroll
            for (int j = 0; j < 8; j++) a[j] += (float)u[j];
        }
        if (act) {
            #pragma unroll
            for (int j = 0; j < 8; j++) a[j] = (a[j] >= 0.f) ? a[j] : 0.01f * a[j];
        }
        half8 o;
        #pragma unroll
        for (int j = 0; j < 8; j++) o[j] = (_Float16)a[j];
        *(half8*)(out + (size_t)d * 128 + f) = o;
    }
}

// ---- dual-output GEMM: P = A@W1, L = A@W2 + b2 (A read ONCE). 64 rows/block, f16 out ----
template <typename AT>
__global__ __launch_bounds__(256) void gemm2_k(const AT* __restrict__ A,
                                               const float* __restrict__ W1,   // [128x128]
                                               const float* __restrict__ W2,   // [128x128]
                                               const float* __restrict__ b2,
                                               _Float16* __restrict__ O1,
                                               _Float16* __restrict__ O2,
                                               int M) {
    constexpr int K = 128;
    constexpr int LDT = K + 8;
    __shared__ _Float16 Wt[256 * LDT];   // 69.6 KB: rows n∈[0,256), n<128→W1, else W2
    int tid = threadIdx.x;
    for (int idx = tid; idx < K * 256; idx += 256) {
        int k = idx >> 8, n = idx & 255;
        float w = (n < 128) ? W1[k * 128 + n] : W2[k * 128 + (n - 128)];
        Wt[n * LDT + k] = (_Float16)w;
    }
    __syncthreads();

    int wave = tid >> 6, lane = tid & 63;
    int quad = lane >> 4, l16 = lane & 15;
    int rowbase = blockIdx.x * 64 + wave * 16;

    f32x4 acc[16];
    f32x4 zero4 = {0.f, 0.f, 0.f, 0.f};
    #pragma unroll
    for (int nt = 0; nt < 16; nt++) acc[nt] = zero4;

    #pragma unroll
    for (int ks = 0; ks < 4; ks++) {
        int k0 = ks * 32 + quad * 8;
        int row = rowbase + l16;
        half8 af = {0, 0, 0, 0, 0, 0, 0, 0};
        if (row < M) {
            if constexpr (sizeof(AT) == 4) {
                const float* ap = (const float*)A + (size_t)row * K + k0;
                float4 x0 = *(const float4*)ap;
                float4 x1 = *(const float4*)(ap + 4);
                af = half8{(_Float16)x0.x, (_Float16)x0.y, (_Float16)x0.z, (_Float16)x0.w,
                           (_Float16)x1.x, (_Float16)x1.y, (_Float16)x1.z, (_Float16)x1.w};
            } else {
                af = *(const half8*)((const _Float16*)A + (size_t)row * K + k0);
            }
        }
        #pragma unroll
        for (int nt = 0; nt < 16; nt++) {
            half8 bfr = *(const half8*)(&Wt[(nt * 16 + l16) * LDT + k0]);
            acc[nt] = __builtin_amdgcn_mfma_f32_16x16x32_f16(af, bfr, acc[nt], 0, 0, 0);
        }
    }

    #pragma unroll
    for (int nt = 0; nt < 16; nt++) {
        int col = nt * 16 + l16;
        bool second = (col >= 128);
        int c = second ? col - 128 : col;
        float bv = second ? b2[c] : 0.f;
        _Float16* O = second ? O2 : O1;
        #pragma unroll
        for (int r = 0; r < 4; r++) {
            int row = rowbase + quad * 4 + r;
            if (row < M) O[(size_t)row * 128 + c] = (_Float16)(acc[nt][r] + bv);
        }
    }
}

// ---- K=256 GEMM: out = leaky(A0@Wrel + A1@(Wroot+Wlin) + brel + blin); A1==Ch in-place safe ----
__global__ __launch_bounds__(256) void gemmk2_k(const _Float16* __restrict__ A0,
                                                const _Float16* A1,
                                                const float* __restrict__ Wrel,
                                                const float* __restrict__ Wroot,
                                                const float* __restrict__ Wlin,
                                                const float* __restrict__ brel,
                                                const float* __restrict__ blin,
                                                float* __restrict__ Cf,    // optional f32 out
                                                _Float16* Ch,              // f16 out (may alias A1)
                                                int M) {
    constexpr int K = 256;
    constexpr int LDT = K + 8;
    constexpr int NT = 8;
    __shared__ _Float16 Wt[128 * LDT];   // 67.6 KB
    int tid = threadIdx.x;
    for (int idx = tid; idx < 128 * 256; idx += 256) {
        int kk = idx >> 7, n = idx & 127;
        float w = (kk < 128) ? Wrel[kk * 128 + n]
                             : Wroot[(kk - 128) * 128 + n] + Wlin[(kk - 128) * 128 + n];
        Wt[n * LDT + kk] = (_Float16)w;
    }
    __syncthreads();

    int wave = tid >> 6, lane = tid & 63;
    int quad = lane >> 4, l16 = lane & 15;
    int rowbase = blockIdx.x * 128 + wave * 32;

    f32x4 acc[2][NT];
    f32x4 zero4 = {0.f, 0.f, 0.f, 0.f};
    #pragma unroll
    for (int mt = 0; mt < 2; mt++)
        #pragma unroll
        for (int nt = 0; nt < NT; nt++) acc[mt][nt] = zero4;

    #pragma unroll
    for (int ks = 0; ks < 8; ks++) {
        int k0 = ks * 32 + quad * 8;
        const _Float16* Asel = (k0 < 128) ? A0 : A1;
        int ka = k0 & 127;
        half8 af[2];
        #pragma unroll
        for (int mt = 0; mt < 2; mt++) {
            int row = rowbase + mt * 16 + l16;
            half8 v = {0, 0, 0, 0, 0, 0, 0, 0};
            if (row < M) v = *(const half8*)(Asel + (size_t)row * 128 + ka);
            af[mt] = v;
        }
        #pragma unroll
        for (int nt = 0; nt < NT; nt++) {
            half8 bfr = *(const half8*)(&Wt[(nt * 16 + l16) * LDT + k0]);
            #pragma unroll
            for (int mt = 0; mt < 2; mt++)
                acc[mt][nt] = __builtin_amdgcn_mfma_f32_16x16x32_f16(af[mt], bfr, acc[mt][nt], 0, 0, 0);
        }
    }

    #pragma unroll
    for (int nt = 0; nt < NT; nt++) {
        int col = nt * 16 + l16;
        float bv = brel[col] + blin[col];
        #pragma unroll
        for (int mt = 0; mt < 2; mt++) {
            #pragma unroll
            for (int r = 0; r < 4; r++) {
                int row = rowbase + mt * 16 + quad * 4 + r;
                if (row < M) {
                    float v = acc[mt][nt][r] + bv;
                    v = (v >= 0.f) ? v : 0.01f * v;
                    if (Cf) Cf[(size_t)row * 128 + col] = v;
                    Ch[(size_t)row * 128 + col] = (_Float16)v;
                }
            }
        }
    }
}

// ---- fc head GEMM: Y = A@W + b, f16 A, f32 out, N=64 ----
__global__ __launch_bounds__(256) void gemmfc_k(const _Float16* __restrict__ A,
                                                const float* __restrict__ W,    // [128x64]
                                                const float* __restrict__ bias,
                                                float* __restrict__ C,
                                                int M) {
    constexpr int K = 128, N = 64;
    constexpr int LDT = K + 8;
    constexpr int NT = N / 16;
    __shared__ _Float16 Wt[N * LDT];
    int tid = threadIdx.x;
    for (int idx = tid; idx < K * N; idx += 256) {
        int k = idx / N, n = idx % N;
        Wt[n * LDT + k] = (_Float16)W[idx];
    }
    __syncthreads();

    int wave = tid >> 6, lane = tid & 63;
    int quad = lane >> 4, l16 = lane & 15;
    int rowbase = blockIdx.x * 128 + wave * 32;

    f32x4 acc[2][NT];
    f32x4 zero4 = {0.f, 0.f, 0.f, 0.f};
    #pragma unroll
    for (int mt = 0; mt < 2; mt++)
        #pragma unroll
        for (int nt = 0; nt < NT; nt++) acc[mt][nt] = zero4;

    #pragma unroll
    for (int ks = 0; ks < 4; ks++) {
        int k0 = ks * 32 + quad * 8;
        half8 af[2];
        #pragma unroll
        for (int mt = 0; mt < 2; mt++) {
            int row = rowbase + mt * 16 + l16;
            half8 v = {0, 0, 0, 0, 0, 0, 0, 0};
            if (row < M) v = *(const half8*)(A + (size_t)row * K + k0);
            af[mt] = v;
        }
        #pragma unroll
        for (int nt = 0; nt < NT; nt++) {
            half8 bfr = *(const half8*)(&Wt[(nt * 16 + l16) * LDT + k0]);
            #pragma unroll
            for (int mt = 0; mt < 2; mt++)
                acc[mt][nt] = __builtin_amdgcn_mfma_f32_16x16x32_f16(af[mt], bfr, acc[mt][nt], 0, 0, 0);
        }
    }

    #pragma unroll
    for (int nt = 0; nt < NT; nt++) {
        int col = nt * 16 + l16;
        float bv = bias[col];
        #pragma unroll
        for (int mt = 0; mt < 2; mt++) {
            #pragma unroll
            for (int r = 0; r < 4; r++) {
                int row = rowbase + mt * 16 + quad * 4 + r;
                if (row < M) C[(size_t)row * N + col] = acc[mt][nt][r] + bv;
            }
        }
    }
}

extern "C" void kernel_launch(void* const* d_in, const int* in_sizes, int n_in,
                              void* d_out, int out_size, void* d_ws, size_t ws_size,
                              hipStream_t stream) {
    const float* X       = (const float*)d_in[0];
    const int*   EIX     = (const int*)d_in[1];
    const int*   HIX     = (const int*)d_in[2];
    const float* hc1_w   = (const float*)d_in[3];
    const float* hc1_b   = (const float*)d_in[4];
    const float* lin1_w  = (const float*)d_in[5];
    const float* lin1_b  = (const float*)d_in[6];
    const float* hc2_w   = (const float*)d_in[7];
    const float* hc2_b   = (const float*)d_in[8];
    const float* lin2_w  = (const float*)d_in[9];
    const float* lin2_b  = (const float*)d_in[10];
    const float* c1_wrel = (const float*)d_in[11];
    const float* c1_brel = (const float*)d_in[12];
    const float* c1_wroot= (const float*)d_in[13];
    const float* glin1_w = (const float*)d_in[14];
    const float* glin1_b = (const float*)d_in[15];
    const float* c2_wrel = (const float*)d_in[16];
    const float* c2_brel = (const float*)d_in[17];
    const float* c2_wroot= (const float*)d_in[18];
    const float* glin2_w = (const float*)d_in[19];
    const float* glin2_b = (const float*)d_in[20];
    const float* fc_w    = (const float*)d_in[21];
    const float* fc_b    = (const float*)d_in[22];

    // ---- workspace carve (~51 MB; ws is 256 MiB per round-5 poison-fill counter) ----
    char* wsp = (char*)d_ws;
    size_t off = 0;
    auto carve = [&](size_t bytes) -> char* {
        char* p = wsp + off;
        off = (off + bytes + 255) & ~(size_t)255;
        return p;
    };
    int*   flags  = (int*)carve(16);
    int*   counts = (int*)carve(110000 * 4);
    int*   offs   = (int*)carve(110003 * 4);
    int*   bsums  = (int*)carve(192 * 4);
    int*   bcur   = (int*)carve(3 * NBK * 4);
    int*   vals   = (int*)carve(2400000 * 4);
    // union: packed pairs (3*NBK*BKCAP*4 = 12.6MB, dead after unbin) vs P+L (25.6MB)
    char*  U      = carve((size_t)NN * 128 * 2 * 2);
    _Float16* P  = (_Float16*)U;                            // 12.8 MB
    _Float16* L  = (_Float16*)(U + (size_t)NN * 128 * 2);   // 12.8 MB
    unsigned* pairs = (unsigned*)U;
    _Float16* MH = (_Float16*)carve((size_t)HECNT * 128 * 2);  // 2.56 MB
    _Float16* XA = (_Float16*)carve((size_t)NN * 128 * 2);     // 12.8 MB f16 chain

    float* XO = (float*)d_out;                 // final X: 50000 x 128 f32
    float* YO = XO + (size_t)NN * 128;         // final y: 50000 x 64 f32

    // ---- CSR build (8 dispatches, no global atomics on hot paths) ----
    detect_k<<<1, 256, 0, stream>>>(EIX, HIX, flags);
    binit_k<<<2, 256, 0, stream>>>(bcur);
    bin_k<<<dim3((EE + CHUNK - 1) / CHUNK, 3), 256, 0, stream>>>(EIX, HIX, flags, bcur, pairs);
    count_k<<<3 * NBK, 256, 0, stream>>>(bcur, pairs, counts);
    scan_p1<<<dim3(49, 3), 256, 0, stream>>>(counts, bsums);
    scan_p2<<<dim3(1, 3), 64, 0, stream>>>(bsums, offs);
    scan_p3<<<dim3(49, 3), 256, 0, stream>>>(counts, bsums, offs);
    unbin_k<<<3 * NBK, 256, 0, stream>>>(offs, pairs, vals);

    const int* offs_he   = offs;                    // [HECNT+1]
    const int* offs_node = offs + HECNT + 1;        // [NN+1]
    const int* offs_dst  = offs + HECNT + NN + 2;   // [NN+1]
    const int* vals_he   = vals;
    const int* vals_node = vals + 800000;
    const int* vals_dst  = vals + 1600000;

    int g64  = (NN + 63) / 64;        // 782  (gemm2)
    int g128 = (NN + 127) / 128;      // 391  (gemmk2 / fc)
    int ghe  = (HECNT + 3) / 4;       // 2500
    int gnn  = (NN + 3) / 4;          // 12500

    // ---- Layer 1: X1 = leaky(Dinv H Binv H^T (X@hc1) + hc1_b + X@lin1 + lin1_b) ----
    gemm2_k<float><<<g64, 256, 0, stream>>>(X, hc1_w, lin1_w, lin1_b, P, L, NN);
    gather_k<<<ghe, 256, 0, stream>>>(offs_he, vals_he, P, MH, HECNT, NN, 1, nullptr, nullptr, 0);
    gather_k<<<gnn, 256, 0, stream>>>(offs_node, vals_node, MH, XA, NN, HECNT, 1, hc1_b, L, 1);

    // ---- Layer 2 ----
    gemm2_k<_Float16><<<g64, 256, 0, stream>>>(XA, hc2_w, lin2_w, lin2_b, P, L, NN);
    gather_k<<<ghe, 256, 0, stream>>>(offs_he, vals_he, P, MH, HECNT, NN, 1, nullptr, nullptr, 0);
    gather_k<<<gnn, 256, 0, stream>>>(offs_node, vals_node, MH, XA, NN, HECNT, 1, hc2_b, L, 1);   // XA = X2

    // ---- Layer 3: X3 = leaky([AGG|X2] @ [Wrel; Wroot+glin1] + brel + glin1_b) ----
    gather_k<<<gnn, 256, 0, stream>>>(offs_dst, vals_dst, XA, P, NN, NN, 0, nullptr, nullptr, 0); // P = AGG
    gemmk2_k<<<g128, 256, 0, stream>>>(P, XA, c1_wrel, c1_wroot, glin1_w, c1_brel, glin1_b,
                                       nullptr, XA, NN);                                          // XA = X3 (in-place)

    // ---- Layer 4: X4 → XO (f32) + XA (f16 for fc) ----
    gather_k<<<gnn, 256, 0, stream>>>(offs_dst, vals_dst, XA, P, NN, NN, 0, nullptr, nullptr, 0);
    gemmk2_k<<<g128, 256, 0, stream>>>(P, XA, c2_wrel, c2_wroot, glin2_w, c2_brel, glin2_b,
                                       XO, XA, NN);

    // ---- fc head ----
    gemmfc_k<<<g128, 256, 0, stream>>>(XA, fc_w, fc_b, YO, NN);
}

// Round 7
// 481.352 us; speedup vs baseline: 2.0988x; 1.1466x over previous
//
#include <hip/hip_runtime.h>

#define NN 50000
#define HECNT 10000
#define EE 800000
#define II 800000
#define NBK 128          // buckets per task (counting sort)
#define CHUNK 4096       // edges per workgroup in bin_k
#define BKCAP 8192       // fixed staging capacity per bucket (mean 6250, +24 sigma)

typedef _Float16 half8 __attribute__((ext_vector_type(8)));
typedef float f32x4    __attribute__((ext_vector_type(4)));

// ---------------- index-width detection ----------------
__global__ void detect_k(const int* __restrict__ EIX, const int* __restrict__ HIX,
                         int* __restrict__ flags) {
    __shared__ int o0, o1;
    int tid = threadIdx.x;
    if (tid == 0) { o0 = 0; o1 = 0; }
    __syncthreads();
    atomicOr(&o0, EIX[2 * tid + 1]);
    atomicOr(&o1, HIX[2 * tid + 1]);
    __syncthreads();
    if (tid == 0) { flags[0] = (o0 == 0); flags[1] = (o1 == 0); }
}

__device__ __forceinline__ int ld_idx(const int* p, long long pos, int is64) {
    return is64 ? p[pos * 2] : p[(int)pos];
}

__device__ __forceinline__ void task_info(int t, int& n, int& cbase, int& obase) {
    if (t == 0)      { n = HECNT; cbase = 0;           obase = 0; }
    else if (t == 1) { n = NN;    cbase = HECNT;       obase = HECNT + 1; }
    else             { n = NN;    cbase = HECNT + NN;  obase = HECNT + NN + 2; }
}

// load (dest, val) for incidence/edge i of task t; dest<0 if invalid
__device__ __forceinline__ void ld_edge(int t, long long i,
                                        const int* EIX, const int* HIX,
                                        int f0, int f1, int& d, int& v) {
    int rng;
    if (t == 0)      { d = ld_idx(HIX, (long long)II + i, f1); v = ld_idx(HIX, i, f1); rng = HECNT; }
    else if (t == 1) { d = ld_idx(HIX, i, f1); v = ld_idx(HIX, (long long)II + i, f1); rng = NN; }
    else             { d = ld_idx(EIX, (long long)EE + i, f0); v = ld_idx(EIX, i, f0); rng = NN; }
    if ((unsigned)d >= (unsigned)rng || (unsigned)v >= 65536u) d = -1;
}

// ---------------- bucket sort with fixed-capacity staging, packed u32 pairs ----------------
__global__ void binit_k(int* __restrict__ bcur) {
    int i = blockIdx.x * 256 + threadIdx.x;
    if (i < 3 * NBK) bcur[i] = i * BKCAP;
}

__global__ __launch_bounds__(256) void bin_k(const int* __restrict__ EIX,
                                             const int* __restrict__ HIX,
                                             const int* __restrict__ flags,
                                             int* __restrict__ bcur,
                                             unsigned* __restrict__ pairs) {
    int t = blockIdx.y;
    __shared__ int hcnt[NBK], hstart[NBK], hrun[NBK], gbase[NBK];
    __shared__ int stot;
    __shared__ unsigned stage[CHUNK];    // 16 KB
    int tid = threadIdx.x;
    int n, cb, ob; task_info(t, n, cb, ob);
    int span = (n + NBK - 1) / NBK;
    long long base = (long long)blockIdx.x * CHUNK;
    int f0 = flags[0], f1 = flags[1];

    for (int i = tid; i < NBK; i += 256) { hcnt[i] = 0; hrun[i] = 0; }
    __syncthreads();

    int d[16], v[16], b[16];
    #pragma unroll
    for (int j = 0; j < 16; j++) {
        long long i = base + j * 256 + tid;
        int dd = -1, vv = 0;
        if (i < EE) ld_edge(t, i, EIX, HIX, f0, f1, dd, vv);
        d[j] = dd; v[j] = vv;
        if (dd >= 0) { b[j] = dd / span; atomicAdd(&hcnt[b[j]], 1); }
    }
    __syncthreads();

    if (tid < NBK) gbase[tid] = hcnt[tid] ? atomicAdd(&bcur[t * NBK + tid], hcnt[tid]) : 0;
    if (tid < NBK) hstart[tid] = hcnt[tid];
    __syncthreads();
    for (int o = 1; o < NBK; o <<= 1) {
        int u = 0;
        if (tid < NBK && tid >= o) u = hstart[tid - o];
        __syncthreads();
        if (tid < NBK) hstart[tid] += u;
        __syncthreads();
    }
    if (tid == NBK - 1) stot = hstart[tid];
    __syncthreads();
    if (tid < NBK) hstart[tid] -= hcnt[tid];   // exclusive
    __syncthreads();

    #pragma unroll
    for (int j = 0; j < 16; j++) {
        if (d[j] >= 0) {
            int p = hstart[b[j]] + atomicAdd(&hrun[b[j]], 1);
            stage[p] = ((unsigned)d[j] << 16) | (unsigned)v[j];
        }
    }
    __syncthreads();

    int total = stot;
    for (int i = tid; i < total; i += 256) {
        int lo = 0, hi = NBK - 1;                  // last bucket with hstart <= i
        while (lo < hi) { int mid = (lo + hi + 1) >> 1; if (hstart[mid] <= i) lo = mid; else hi = mid - 1; }
        int pos = gbase[lo] + (i - hstart[lo]);
        if (pos < (t * NBK + lo + 1) * BKCAP)      // capacity clamp (never expected)
            pairs[pos] = stage[i];
    }
}

// per-bucket dest histogram from staged pairs — LDS atomics only, coalesced writes
__global__ __launch_bounds__(256) void count_k(const int* __restrict__ bcur,
                                               const unsigned* __restrict__ pairs,
                                               int* __restrict__ counts) {
    int idx = blockIdx.x;              // 0 .. 3*NBK-1
    int t = idx / NBK, b = idx % NBK;
    int n, cb, ob; task_info(t, n, cb, ob);
    int span = (n + NBK - 1) / NBK;
    int dlo = min(b * span, n), dhi = min(dlo + span, n);
    __shared__ int hist[400];
    int tid = threadIdx.x;
    for (int i = tid; i < dhi - dlo; i += 256) hist[i] = 0;
    __syncthreads();
    int cnt = min(bcur[idx] - idx * BKCAP, BKCAP);
    const unsigned* pw = pairs + (size_t)idx * BKCAP;
    for (int i = tid; i < cnt; i += 256) {
        int dl = (int)(pw[i] >> 16) - dlo;
        if ((unsigned)dl < (unsigned)(dhi - dlo)) atomicAdd(&hist[dl], 1);
    }
    __syncthreads();
    for (int i = tid; i < dhi - dlo; i += 256) counts[cb + dlo + i] = hist[i];
}

__global__ __launch_bounds__(256) void scan_p1(const int* __restrict__ counts,
                                               int* __restrict__ bsums) {
    int t = blockIdx.y;
    int n, cb, ob; task_info(t, n, cb, ob);
    int base = blockIdx.x * 1024 + threadIdx.x * 4;
    int s = 0;
    #pragma unroll
    for (int j = 0; j < 4; j++) { int i = base + j; if (i < n) s += counts[cb + i]; }
    __shared__ int red[256];
    red[threadIdx.x] = s; __syncthreads();
    for (int o = 128; o > 0; o >>= 1) {
        if (threadIdx.x < o) red[threadIdx.x] += red[threadIdx.x + o];
        __syncthreads();
    }
    if (threadIdx.x == 0) bsums[t * 64 + blockIdx.x] = red[0];
}

__global__ void scan_p2(int* __restrict__ bsums, int* __restrict__ offs) {
    int t = blockIdx.y;
    int n, cb, ob; task_info(t, n, cb, ob);
    int lane = threadIdx.x;
    int nb = (n + 1023) / 1024;
    int v = (lane < nb) ? bsums[t * 64 + lane] : 0;
    int incl = v;
    for (int d = 1; d < 64; d <<= 1) {
        int u = __shfl_up(incl, (unsigned)d, 64);
        if (lane >= d) incl += u;
    }
    bsums[t * 64 + lane] = incl - v;           // exclusive block sums
    int total = __shfl(incl, 63, 64);
    if (lane == 0) offs[ob + n] = total;
}

__global__ __launch_bounds__(256) void scan_p3(const int* __restrict__ counts,
                                               const int* __restrict__ bsums,
                                               int* __restrict__ offs) {
    int t = blockIdx.y;
    int n, cb, ob; task_info(t, n, cb, ob);
    int tid = threadIdx.x;
    int base = blockIdx.x * 1024 + tid * 4;
    int c[4]; int s = 0;
    #pragma unroll
    for (int j = 0; j < 4; j++) { int i = base + j; c[j] = (i < n) ? counts[cb + i] : 0; s += c[j]; }
    __shared__ int sc[256];
    sc[tid] = s; __syncthreads();
    for (int o = 1; o < 256; o <<= 1) {
        int v = (tid >= o) ? sc[tid - o] : 0;
        __syncthreads();
        sc[tid] += v;
        __syncthreads();
    }
    int excl = sc[tid] - s;
    int p = bsums[t * 64 + blockIdx.x] + excl;
    #pragma unroll
    for (int j = 0; j < 4; j++) {
        int i = base + j;
        if (i < n) { offs[ob + i] = p; p += c[j]; }
    }
}

// per-bucket exact CSR placement via LDS window, coalesced flush
__global__ __launch_bounds__(256) void unbin_k(const int* __restrict__ offs,
                                               const unsigned* __restrict__ pairs,
                                               int* __restrict__ vals) {
    int idx = blockIdx.x;              // 0 .. 3*NBK-1
    int t = idx / NBK, b = idx % NBK;
    int n, cb, ob; task_info(t, n, cb, ob);
    int span = (n + NBK - 1) / NBK;
    int dlo = min(b * span, n), dhi = min(dlo + span, n);
    if (dhi <= dlo) return;
    int p0 = offs[ob + dlo], p1 = offs[ob + dhi];
    int cnt = p1 - p0;                 // == staged count (counts derived from staging)
    __shared__ int win[BKCAP];         // 32 KB
    __shared__ int cur[400];
    int tid = threadIdx.x;
    for (int i = tid; i < dhi - dlo; i += 256) cur[i] = offs[ob + dlo + i] - p0;
    __syncthreads();
    const unsigned* pw = pairs + (size_t)idx * BKCAP;
    int* vw = vals + (size_t)t * 800000 + p0;
    if (cnt > BKCAP) cnt = BKCAP;
    for (int i = tid; i < cnt; i += 256) {
        unsigned pv = pw[i];
        int dl = (int)(pv >> 16) - dlo;
        if ((unsigned)dl < (unsigned)(dhi - dlo)) {
            int p = atomicAdd(&cur[dl], 1);
            if ((unsigned)p < (unsigned)BKCAP) win[p] = (int)(pv & 0xffffu);
        }
    }
    __syncthreads();
    for (int i = tid; i < cnt; i += 256) vw[i] = win[i];
}

// ------- gather: 1 dest/wave, 16 lanes x half8, 4 edges in flight; epilogue finishes the layer -------
__global__ __launch_bounds__(256) void gather_k(const int* __restrict__ offs,
                                                const int* __restrict__ vals,
                                                const _Float16* __restrict__ src,   // [S x 128] f16
                                                _Float16* __restrict__ out,         // [ndst x 128] f16
                                                int ndst, int nsrc, int scale_flag,
                                                const float* __restrict__ bias,
                                                const _Float16* __restrict__ addend,
                                                int act) {
    int wave = threadIdx.x >> 6, lane = threadIdx.x & 63;
    int sub = lane >> 4, l16 = lane & 15;
    int d = blockIdx.x * 4 + wave;
    if (d >= ndst) return;
    int beg = offs[d], end = offs[d + 1];
    int f = l16 * 8;
    float a[8] = {0.f, 0.f, 0.f, 0.f, 0.f, 0.f, 0.f, 0.f};
    auto acc_row = [&](int s) {
        if ((unsigned)s < (unsigned)nsrc) {
            half8 u = *(const half8*)(src + (size_t)s * 128 + f);
            #pragma unroll
            for (int j = 0; j < 8; j++) a[j] += (float)u[j];
        }
    };
    int e = beg + sub;
    for (; e + 4 < end; e += 8) {            // 8 rows in flight per wave
        int s0 = vals[e], s1 = vals[e + 4];
        acc_row(s0); acc_row(s1);
    }
    if (e < end) acc_row(vals[e]);
    #pragma unroll
    for (int j = 0; j < 8; j++) {
        a[j] += __shfl_xor(a[j], 16, 64);
        a[j] += __shfl_xor(a[j], 32, 64);
    }
    if (sub == 0) {
        if (scale_flag) {
            int c = end - beg;
            float iv = (c > 0) ? 1.f / (float)c : 0.f;
            #pragma unroll
            for (int j = 0; j < 8; j++) a[j] *= iv;
        }
        if (bias) {
            f32x4 b0 = *(const f32x4*)(bias + f);
            f32x4 b1 = *(const f32x4*)(bias + f + 4);
            #pragma unroll
            for (int j = 0; j < 4; j++) { a[j] += b0[j]; a[4 + j] += b1[j]; }
        }
        if (addend) {
            half8 u = *(const half8*)(addend + (size_t)d * 128 + f);
            #pragma unroll
            for (int j = 0; j < 8; j++) a[j] += (float)u[j];
        }
        if (act) {
            #pragma unroll
            for (int j = 0; j < 8; j++) a[j] = (a[j] >= 0.f) ? a[j] : 0.01f * a[j];
        }
        half8 o;
        #pragma unroll
        for (int j = 0; j < 8; j++) o[j] = (_Float16)a[j];
        *(half8*)(out + (size_t)d * 128 + f) = o;
    }
}

// ---- one-time weight prep: write W in MFMA B-fragment order (half8 per lane) ----
// set 0: [hc1|lin1] KS=4 NT=16; set 1: [hc2|lin2]; set 2: [c1_wrel; c1_wroot+glin1] KS=8 NT=8;
// set 3: layer-4 same; set 4: fc_w KS=4 NT=4.
__global__ __launch_bounds__(256) void wprep_k(const float* __restrict__ hc1_w, const float* __restrict__ lin1_w,
                                               const float* __restrict__ hc2_w, const float* __restrict__ lin2_w,
                                               const float* __restrict__ c1_wrel, const float* __restrict__ c1_wroot,
                                               const float* __restrict__ glin1_w,
                                               const float* __restrict__ c2_wrel, const float* __restrict__ c2_wroot,
                                               const float* __restrict__ glin2_w,
                                               const float* __restrict__ fc_w,
                                               _Float16* __restrict__ F) {
    int set = blockIdx.y;
    int nfrag = (set == 4) ? 1024 : 4096;   // # of half8 fragments
    int NT = (set < 2) ? 16 : (set == 4 ? 4 : 8);
    int fid = blockIdx.x * 256 + threadIdx.x;
    if (fid >= nfrag) return;
    int lane = fid & 63;
    int tile = fid >> 6;                    // ks*NT + nt
    int nt = tile % NT, ks = tile / NT;
    int n = nt * 16 + (lane & 15);
    int kbase = ks * 32 + (lane >> 4) * 8;
    _Float16* dst = F + (size_t)set * 32768 + (size_t)fid * 8;
    #pragma unroll
    for (int j = 0; j < 8; j++) {
        int k = kbase + j;
        float w;
        if (set == 0)      w = (n < 128) ? hc1_w[k * 128 + n] : lin1_w[k * 128 + n - 128];
        else if (set == 1) w = (n < 128) ? hc2_w[k * 128 + n] : lin2_w[k * 128 + n - 128];
        else if (set == 2) w = (k < 128) ? c1_wrel[k * 128 + n]
                                         : c1_wroot[(k - 128) * 128 + n] + glin1_w[(k - 128) * 128 + n];
        else if (set == 3) w = (k < 128) ? c2_wrel[k * 128 + n]
                                         : c2_wroot[(k - 128) * 128 + n] + glin2_w[(k - 128) * 128 + n];
        else               w = fc_w[k * 64 + n];
        dst[j] = (_Float16)w;
    }
}

// ---- dual-output GEMM, LDS-free: P = A@W1, L = A@W2 + b2. B-frags from global (L2-hot). ----
template <typename AT>
__global__ __launch_bounds__(256) void gemm2_k(const AT* __restrict__ A,
                                               const half8* __restrict__ Bf,   // KS=4, NT=16
                                               const float* __restrict__ b2,
                                               _Float16* __restrict__ O1,
                                               _Float16* __restrict__ O2,
                                               int M) {
    constexpr int K = 128, NT = 16;
    int tid = threadIdx.x;
    int wave = tid >> 6, lane = tid & 63;
    int quad = lane >> 4, l16 = lane & 15;
    int rowbase = blockIdx.x * 64 + wave * 16;
    int row = rowbase + l16;

    f32x4 acc[NT];
    f32x4 zero4 = {0.f, 0.f, 0.f, 0.f};
    #pragma unroll
    for (int nt = 0; nt < NT; nt++) acc[nt] = zero4;

    #pragma unroll
    for (int ks = 0; ks < 4; ks++) {
        int k0 = ks * 32 + quad * 8;
        half8 af = {0, 0, 0, 0, 0, 0, 0, 0};
        if (row < M) {
            if constexpr (sizeof(AT) == 4) {
                const float* ap = (const float*)A + (size_t)row * K + k0;
                float4 x0 = *(const float4*)ap;
                float4 x1 = *(const float4*)(ap + 4);
                af = half8{(_Float16)x0.x, (_Float16)x0.y, (_Float16)x0.z, (_Float16)x0.w,
                           (_Float16)x1.x, (_Float16)x1.y, (_Float16)x1.z, (_Float16)x1.w};
            } else {
                af = *(const half8*)((const _Float16*)A + (size_t)row * K + k0);
            }
        }
        #pragma unroll
        for (int nt = 0; nt < NT; nt++) {
            half8 bfr = Bf[(ks * NT + nt) * 64 + lane];
            acc[nt] = __builtin_amdgcn_mfma_f32_16x16x32_f16(af, bfr, acc[nt], 0, 0, 0);
        }
    }

    #pragma unroll
    for (int nt = 0; nt < NT; nt++) {
        int col = nt * 16 + l16;
        bool second = (col >= 128);
        int c = second ? col - 128 : col;
        float bv = second ? b2[c] : 0.f;
        _Float16* O = second ? O2 : O1;
        #pragma unroll
        for (int r = 0; r < 4; r++) {
            int rr = rowbase + quad * 4 + r;
            if (rr < M) O[(size_t)rr * 128 + c] = (_Float16)(acc[nt][r] + bv);
        }
    }
}

// ---- K=256 GEMM, LDS-free: out = leaky(A0@Wrel + A1@(Wroot+Wlin) + brel + blin) ----
__global__ __launch_bounds__(256) void gemmk2_k(const _Float16* __restrict__ A0,
                                                const _Float16* A1,
                                                const half8* __restrict__ Bf,   // KS=8, NT=8
                                                const float* __restrict__ brel,
                                                const float* __restrict__ blin,
                                                float* __restrict__ Cf,    // optional f32 out
                                                _Float16* Ch,              // f16 out (may alias A1)
                                                int M) {
    constexpr int NT = 8;
    int tid = threadIdx.x;
    int wave = tid >> 6, lane = tid & 63;
    int quad = lane >> 4, l16 = lane & 15;
    int rowbase = blockIdx.x * 64 + wave * 16;
    int row = rowbase + l16;

    f32x4 acc[NT];
    f32x4 zero4 = {0.f, 0.f, 0.f, 0.f};
    #pragma unroll
    for (int nt = 0; nt < NT; nt++) acc[nt] = zero4;

    #pragma unroll
    for (int ks = 0; ks < 8; ks++) {
        int k0 = ks * 32 + quad * 8;
        const _Float16* Asel = (k0 < 128) ? A0 : A1;
        int ka = k0 & 127;
        half8 af = {0, 0, 0, 0, 0, 0, 0, 0};
        if (row < M) af = *(const half8*)(Asel + (size_t)row * 128 + ka);
        #pragma unroll
        for (int nt = 0; nt < NT; nt++) {
            half8 bfr = Bf[(ks * NT + nt) * 64 + lane];
            acc[nt] = __builtin_amdgcn_mfma_f32_16x16x32_f16(af, bfr, acc[nt], 0, 0, 0);
        }
    }

    // all A-reads for this wave's 16-row band done; epilogue writes same band only
    #pragma unroll
    for (int nt = 0; nt < NT; nt++) {
        int col = nt * 16 + l16;
        float bv = brel[col] + blin[col];
        #pragma unroll
        for (int r = 0; r < 4; r++) {
            int rr = rowbase + quad * 4 + r;
            if (rr < M) {
                float v = acc[nt][r] + bv;
                v = (v >= 0.f) ? v : 0.01f * v;
                if (Cf) Cf[(size_t)rr * 128 + col] = v;
                Ch[(size_t)rr * 128 + col] = (_Float16)v;
            }
        }
    }
}

// ---- fc head GEMM, LDS-free: Y = A@W + b, N=64 ----
__global__ __launch_bounds__(256) void gemmfc_k(const _Float16* __restrict__ A,
                                                const half8* __restrict__ Bf,   // KS=4, NT=4
                                                const float* __restrict__ bias,
                                                float* __restrict__ C,
                                                int M) {
    constexpr int K = 128, N = 64, NT = 4;
    int tid = threadIdx.x;
    int wave = tid >> 6, lane = tid & 63;
    int quad = lane >> 4, l16 = lane & 15;
    int rowbase = blockIdx.x * 64 + wave * 16;
    int row = rowbase + l16;

    f32x4 acc[NT];
    f32x4 zero4 = {0.f, 0.f, 0.f, 0.f};
    #pragma unroll
    for (int nt = 0; nt < NT; nt++) acc[nt] = zero4;

    #pragma unroll
    for (int ks = 0; ks < 4; ks++) {
        int k0 = ks * 32 + quad * 8;
        half8 af = {0, 0, 0, 0, 0, 0, 0, 0};
        if (row < M) af = *(const half8*)(A + (size_t)row * K + k0);
        #pragma unroll
        for (int nt = 0; nt < NT; nt++) {
            half8 bfr = Bf[(ks * NT + nt) * 64 + lane];
            acc[nt] = __builtin_amdgcn_mfma_f32_16x16x32_f16(af, bfr, acc[nt], 0, 0, 0);
        }
    }

    #pragma unroll
    for (int nt = 0; nt < NT; nt++) {
        int col = nt * 16 + l16;
        float bv = bias[col];
        #pragma unroll
        for (int r = 0; r < 4; r++) {
            int rr = rowbase + quad * 4 + r;
            if (rr < M) C[(size_t)rr * N + col] = acc[nt][r] + bv;
        }
    }
}

extern "C" void kernel_launch(void* const* d_in, const int* in_sizes, int n_in,
                              void* d_out, int out_size, void* d_ws, size_t ws_size,
                              hipStream_t stream) {
    const float* X       = (const float*)d_in[0];
    const int*   EIX     = (const int*)d_in[1];
    const int*   HIX     = (const int*)d_in[2];
    const float* hc1_w   = (const float*)d_in[3];
    const float* hc1_b   = (const float*)d_in[4];
    const float* lin1_w  = (const float*)d_in[5];
    const float* lin1_b  = (const float*)d_in[6];
    const float* hc2_w   = (const float*)d_in[7];
    const float* hc2_b   = (const float*)d_in[8];
    const float* lin2_w  = (const float*)d_in[9];
    const float* lin2_b  = (const float*)d_in[10];
    const float* c1_wrel = (const float*)d_in[11];
    const float* c1_brel = (const float*)d_in[12];
    const float* c1_wroot= (const float*)d_in[13];
    const float* glin1_w = (const float*)d_in[14];
    const float* glin1_b = (const float*)d_in[15];
    const float* c2_wrel = (const float*)d_in[16];
    const float* c2_brel = (const float*)d_in[17];
    const float* c2_wroot= (const float*)d_in[18];
    const float* glin2_w = (const float*)d_in[19];
    const float* glin2_b = (const float*)d_in[20];
    const float* fc_w    = (const float*)d_in[21];
    const float* fc_b    = (const float*)d_in[22];

    // ---- workspace carve (~52 MB; ws is 256 MiB per round-5 poison-fill counter) ----
    char* wsp = (char*)d_ws;
    size_t off = 0;
    auto carve = [&](size_t bytes) -> char* {
        char* p = wsp + off;
        off = (off + bytes + 255) & ~(size_t)255;
        return p;
    };
    int*   flags  = (int*)carve(16);
    int*   counts = (int*)carve(110000 * 4);
    int*   offs   = (int*)carve(110003 * 4);
    int*   bsums  = (int*)carve(192 * 4);
    int*   bcur   = (int*)carve(3 * NBK * 4);
    int*   vals   = (int*)carve(2400000 * 4);
    _Float16* F   = (_Float16*)carve((4 * 32768 + 8192) * 2);   // frag-ordered weights, 272 KB
    // union: packed pairs (3*NBK*BKCAP*4 = 12.6MB, dead after unbin) vs P+L (25.6MB)
    char*  U      = carve((size_t)NN * 128 * 2 * 2);
    _Float16* P  = (_Float16*)U;                            // 12.8 MB
    _Float16* L  = (_Float16*)(U + (size_t)NN * 128 * 2);   // 12.8 MB
    unsigned* pairs = (unsigned*)U;
    _Float16* MH = (_Float16*)carve((size_t)HECNT * 128 * 2);  // 2.56 MB
    _Float16* XA = (_Float16*)carve((size_t)NN * 128 * 2);     // 12.8 MB f16 chain

    float* XO = (float*)d_out;                 // final X: 50000 x 128 f32
    float* YO = XO + (size_t)NN * 128;         // final y: 50000 x 64 f32

    const half8* F0 = (const half8*)F;                     // L1 [hc1|lin1]
    const half8* F1 = (const half8*)(F + 32768);           // L2
    const half8* F2 = (const half8*)(F + 2 * 32768);       // L3
    const half8* F3 = (const half8*)(F + 3 * 32768);       // L4
    const half8* F4 = (const half8*)(F + 4 * 32768);       // fc

    // ---- CSR build + weight prep ----
    detect_k<<<1, 256, 0, stream>>>(EIX, HIX, flags);
    binit_k<<<2, 256, 0, stream>>>(bcur);
    wprep_k<<<dim3(16, 5), 256, 0, stream>>>(hc1_w, lin1_w, hc2_w, lin2_w,
                                             c1_wrel, c1_wroot, glin1_w,
                                             c2_wrel, c2_wroot, glin2_w, fc_w, F);
    bin_k<<<dim3((EE + CHUNK - 1) / CHUNK, 3), 256, 0, stream>>>(EIX, HIX, flags, bcur, pairs);
    count_k<<<3 * NBK, 256, 0, stream>>>(bcur, pairs, counts);
    scan_p1<<<dim3(49, 3), 256, 0, stream>>>(counts, bsums);
    scan_p2<<<dim3(1, 3), 64, 0, stream>>>(bsums, offs);
    scan_p3<<<dim3(49, 3), 256, 0, stream>>>(counts, bsums, offs);
    unbin_k<<<3 * NBK, 256, 0, stream>>>(offs, pairs, vals);

    const int* offs_he   = offs;                    // [HECNT+1]
    const int* offs_node = offs + HECNT + 1;        // [NN+1]
    const int* offs_dst  = offs + HECNT + NN + 2;   // [NN+1]
    const int* vals_he   = vals;
    const int* vals_node = vals + 800000;
    const int* vals_dst  = vals + 1600000;

    int g64 = (NN + 63) / 64;         // 782
    int ghe = (HECNT + 3) / 4;        // 2500
    int gnn = (NN + 3) / 4;           // 12500

    // ---- Layer 1: X1 = leaky(Dinv H Binv H^T (X@hc1) + hc1_b + X@lin1 + lin1_b) ----
    gemm2_k<float><<<g64, 256, 0, stream>>>(X, F0, lin1_b, P, L, NN);
    gather_k<<<ghe, 256, 0, stream>>>(offs_he, vals_he, P, MH, HECNT, NN, 1, nullptr, nullptr, 0);
    gather_k<<<gnn, 256, 0, stream>>>(offs_node, vals_node, MH, XA, NN, HECNT, 1, hc1_b, L, 1);

    // ---- Layer 2 ----
    gemm2_k<_Float16><<<g64, 256, 0, stream>>>(XA, F1, lin2_b, P, L, NN);
    gather_k<<<ghe, 256, 0, stream>>>(offs_he, vals_he, P, MH, HECNT, NN, 1, nullptr, nullptr, 0);
    gather_k<<<gnn, 256, 0, stream>>>(offs_node, vals_node, MH, XA, NN, HECNT, 1, hc2_b, L, 1);   // XA = X2

    // ---- Layer 3: X3 = leaky([AGG|X2] @ [Wrel; Wroot+glin1] + brel + glin1_b) ----
    gather_k<<<gnn, 256, 0, stream>>>(offs_dst, vals_dst, XA, P, NN, NN, 0, nullptr, nullptr, 0); // P = AGG
    gemmk2_k<<<g64, 256, 0, stream>>>(P, XA, F2, c1_brel, glin1_b, nullptr, XA, NN);              // XA = X3

    // ---- Layer 4: X4 → XO (f32) + XA (f16 for fc) ----
    gather_k<<<gnn, 256, 0, stream>>>(offs_dst, vals_dst, XA, P, NN, NN, 0, nullptr, nullptr, 0);
    gemmk2_k<<<g64, 256, 0, stream>>>(P, XA, F3, c2_brel, glin2_b, XO, XA, NN);

    // ---- fc head ----
    gemmfc_k<<<g64, 256, 0, stream>>>(XA, F4, fc_b, YO, NN);
}